// Round 13
// baseline (1824.612 us; speedup 1.0000x reference)
//
#include <hip/hip_runtime.h>
#include <hip/hip_bf16.h>

typedef __bf16 bf16_t;
typedef __bf16 bf16x8 __attribute__((ext_vector_type(8)));
typedef __bf16 bf16x4 __attribute__((ext_vector_type(4)));
typedef float f32x4 __attribute__((ext_vector_type(4)));

#define NB 4
#define NT 1024
#define NO 128
#define NC 1024
#define NH 16
#define NL 4
#define NV 32000
#define NS 4096
#define ND 64
#define NTK (NO + NT)   // 1152

#define GLOAD_LDS16(g, l) __builtin_amdgcn_global_load_lds( \
    (__attribute__((address_space(1))) void*)(g), \
    (__attribute__((address_space(3))) void*)(l), 16, 0, 0)

__device__ __forceinline__ float sigmoidf_(float x) { return 1.0f / (1.0f + __expf(-x)); }

#define EPI_F32  0
#define EPI_ADD  1
#define EPI_GELU 2
#define EPI_QKV  3
#define EPI_KV   4

// ---------------------------------------------------------------------------
// 8-wave 256x256 GEMM (round-6 engine): BK=64, 512 thr, double-buffered
// 128KB LDS, counted vmcnt, raw s_barrier, XOR swizzle, fragment reuse.
// EPI 0: f32 nontemporal; 1: GELU->bf16.
// ---------------------------------------------------------------------------
template<int EPI>
__global__ __launch_bounds__(512) void gemm8p(
    const bf16_t* __restrict__ A, const bf16_t* __restrict__ Bt,
    const float* __restrict__ bias, float* __restrict__ outF,
    bf16_t* __restrict__ outB, int M, int N, int K, int ldo, int gm)
{
    __shared__ bf16_t sm[65536];
    const int tid = threadIdx.x;
    const int w = tid >> 6, lane = tid & 63;
    const int wr = w >> 2, wc = w & 3;
    const int lr = lane & 15, lk = lane >> 4;
    const int nwg = gridDim.x;
    const int bid = blockIdx.x;
    const int xcd = bid & 7, base = bid >> 3;
    const int qq = nwg >> 3, rr = nwg & 7;
    int wg = (xcd < rr ? xcd * (qq + 1) : rr * (qq + 1) + (xcd - rr) * qq) + base;
    const int nnt = N >> 8;
    const int gsz = gm * nnt;
    const int g = wg / gsz, r2 = wg - g * gsz;
    const int ntl = r2 / gm, mt = g * gm + (r2 - ntl * gm);
    const int bm = mt << 8, bn = ntl << 8;
    const bf16_t* Ab = A + (size_t)bm * K;
    const bf16_t* Bb = Bt + (size_t)bn * K;
    const int srow = tid >> 3;
    const int scol = ((tid & 7) ^ (srow & 7)) << 3;
    const int nk = K >> 6;
    f32x4 acc[8][4] = {};

    auto STAGE = [&](int b, int kt, int h) {
        const bf16_t* gsrc = (h < 2) ? Ab : Bb;
        const int half = h & 1;
        char* lbase = (char*)(sm + ((h < 2) ? 0 : 32768) + b * 16384 + half * 8192);
        #pragma unroll
        for (int i = 0; i < 2; ++i) {
            GLOAD_LDS16(gsrc + (size_t)(half * 128 + i * 64 + srow) * K + kt * 64 + scol,
                        lbase + (i * 512 + tid) * 16);
        }
    };

    #pragma unroll
    for (int h = 0; h < 4; ++h) STAGE(0, 0, h);
    asm volatile("s_waitcnt vmcnt(0)" ::: "memory");
    __builtin_amdgcn_s_barrier();

    for (int kt = 0; kt < nk; ++kt) {
        const int curb = kt & 1;
        const bool dostage = (kt + 1) < nk;
        const char* Abase = (const char*)(sm + curb * 16384);
        const char* Bbase = (const char*)(sm + 32768 + curb * 16384);

        if (dostage) {
            STAGE(curb ^ 1, kt + 1, 0);
            STAGE(curb ^ 1, kt + 1, 1);
            asm volatile("s_waitcnt vmcnt(4)" ::: "memory");
        } else {
            asm volatile("s_waitcnt vmcnt(0)" ::: "memory");
        }
        __builtin_amdgcn_s_barrier();

        bf16x8 bfr[4][2];
        #pragma unroll
        for (int n = 0; n < 4; ++n)
            #pragma unroll
            for (int ks = 0; ks < 2; ++ks) {
                const int row = wc * 64 + n * 16 + lr;
                bfr[n][ks] = *(const bf16x8*)(Bbase + row * 128 + ((((ks << 2) + lk) ^ (row & 7)) << 4));
            }
        bf16x8 af[4][2];
        #pragma unroll
        for (int m = 0; m < 4; ++m)
            #pragma unroll
            for (int ks = 0; ks < 2; ++ks) {
                const int row = wr * 128 + m * 16 + lr;
                af[m][ks] = *(const bf16x8*)(Abase + row * 128 + ((((ks << 2) + lk) ^ (row & 7)) << 4));
            }
        asm volatile("s_waitcnt lgkmcnt(0)" ::: "memory");
        __builtin_amdgcn_sched_barrier(0);
        __builtin_amdgcn_s_setprio(1);
        #pragma unroll
        for (int m = 0; m < 4; ++m)
            #pragma unroll
            for (int n = 0; n < 4; ++n)
                #pragma unroll
                for (int ks = 0; ks < 2; ++ks)
                    acc[m][n] = __builtin_amdgcn_mfma_f32_16x16x32_bf16(
                        af[m][ks], bfr[n][ks], acc[m][n], 0, 0, 0);
        __builtin_amdgcn_s_setprio(0);

        if (dostage) {
            STAGE(curb ^ 1, kt + 1, 2);
            STAGE(curb ^ 1, kt + 1, 3);
        }
        bf16x8 ag[4][2];
        #pragma unroll
        for (int m = 0; m < 4; ++m)
            #pragma unroll
            for (int ks = 0; ks < 2; ++ks) {
                const int row = wr * 128 + 64 + m * 16 + lr;
                ag[m][ks] = *(const bf16x8*)(Abase + row * 128 + ((((ks << 2) + lk) ^ (row & 7)) << 4));
            }
        asm volatile("s_waitcnt lgkmcnt(0)" ::: "memory");
        __builtin_amdgcn_sched_barrier(0);
        __builtin_amdgcn_s_setprio(1);
        #pragma unroll
        for (int m = 0; m < 4; ++m)
            #pragma unroll
            for (int n = 0; n < 4; ++n)
                #pragma unroll
                for (int ks = 0; ks < 2; ++ks)
                    acc[4 + m][n] = __builtin_amdgcn_mfma_f32_16x16x32_bf16(
                        ag[m][ks], bfr[n][ks], acc[4 + m][n], 0, 0, 0);
        __builtin_amdgcn_s_setprio(0);
        __builtin_amdgcn_s_barrier();
    }

    float bv4[4];
    #pragma unroll
    for (int n = 0; n < 4; ++n) bv4[n] = bias[bn + wc * 64 + n * 16 + lr];
    #pragma unroll
    for (int m = 0; m < 8; ++m) {
        #pragma unroll
        for (int j = 0; j < 4; ++j) {
            const int row = bm + wr * 128 + m * 16 + lk * 4 + j;
            #pragma unroll
            for (int n = 0; n < 4; ++n) {
                const int col = bn + wc * 64 + n * 16 + lr;
                float v = acc[m][n][j] + bv4[n];
                if constexpr (EPI == 0) {
                    __builtin_nontemporal_store(v, &outF[(size_t)row * ldo + col]);
                } else {
                    float u = 1.5957691216057308f * (v + 0.044715f * v * v * v);
                    float g_ = v / (1.0f + __expf(-u));
                    outB[(size_t)row * ldo + col] = (bf16_t)g_;
                }
            }
        }
    }
}

// ---------------------------------------------------------------------------
// 4-wave 128x128 GEMM, round-6 schedule: BK=64, 256 thr, 64 KB LDS
// (2 blocks/CU), counted vmcnt(4), XOR swizzle, B-frags held across both
// ks-phases.
// ---------------------------------------------------------------------------
template<int EPI>
__global__ __launch_bounds__(256) void gemm128(
    const bf16_t* __restrict__ A, const bf16_t* __restrict__ Bt,
    const float* __restrict__ bias, const float* __restrict__ bias2,
    float* __restrict__ outF, bf16_t* __restrict__ outB, bf16_t* __restrict__ outB2,
    int M, int N, int K, int p0, int ldo, int gm)
{
    __shared__ bf16_t sm[32768];  // 64 KB
    char* smb = (char*)sm;
    const int tid = threadIdx.x;
    const int w = tid >> 6, lane = tid & 63;
    const int wr = w >> 1, wc = w & 1;
    const int lr = lane & 15, lk = lane >> 4;
    const int nwg = gridDim.x;
    const int bid = blockIdx.x;
    const int xcd = bid & 7, base = bid >> 3;
    const int qq = nwg >> 3, rr = nwg & 7;
    int wg = (xcd < rr ? xcd * (qq + 1) : rr * (qq + 1) + (xcd - rr) * qq) + base;
    const int nnt = N >> 7;
    const int gsz = gm * nnt;
    const int g = wg / gsz, r2 = wg - g * gsz;
    const int ntl = r2 / gm, mt = g * gm + (r2 - ntl * gm);
    const int bm = mt << 7, bn = ntl << 7;
    const bf16_t* Ab = A + (size_t)bm * K;
    const bf16_t* Bb = Bt + (size_t)bn * K;
    const int srow = tid >> 3;
    const int scol = ((tid & 7) ^ (srow & 7)) << 3;
    const int nk = K >> 6;
    f32x4 acc[4][4] = {};

    auto STAGE = [&](int b, int kt, int h) {
        const bf16_t* gsrc = h ? Bb : Ab;
        char* lbase = smb + h * 32768 + b * 16384;
        #pragma unroll
        for (int i = 0; i < 4; ++i) {
            GLOAD_LDS16(gsrc + (size_t)(i * 32 + srow) * K + kt * 64 + scol,
                        lbase + (i * 256 + tid) * 16);
        }
    };

    STAGE(0, 0, 0); STAGE(0, 0, 1);
    asm volatile("s_waitcnt vmcnt(0)" ::: "memory");
    __builtin_amdgcn_s_barrier();

    for (int kt = 0; kt < nk; ++kt) {
        const int curb = kt & 1;
        const bool dostage = (kt + 1) < nk;
        const char* Abase = smb + curb * 16384;
        const char* Bbase = smb + 32768 + curb * 16384;

        if (dostage) {
            STAGE(curb ^ 1, kt + 1, 0);
            asm volatile("s_waitcnt vmcnt(4)" ::: "memory");
        } else {
            asm volatile("s_waitcnt vmcnt(0)" ::: "memory");
        }
        __builtin_amdgcn_s_barrier();

        bf16x8 bfr[4][2];
        #pragma unroll
        for (int n = 0; n < 4; ++n)
            #pragma unroll
            for (int ks_ = 0; ks_ < 2; ++ks_) {
                const int row = wc * 64 + n * 16 + lr;
                bfr[n][ks_] = *(const bf16x8*)(Bbase + row * 128 + ((((ks_ << 2) + lk) ^ (row & 7)) << 4));
            }
        bf16x8 af[4];
        #pragma unroll
        for (int m = 0; m < 4; ++m) {
            const int row = wr * 64 + m * 16 + lr;
            af[m] = *(const bf16x8*)(Abase + row * 128 + (((lk) ^ (row & 7)) << 4));
        }
        asm volatile("s_waitcnt lgkmcnt(0)" ::: "memory");
        __builtin_amdgcn_sched_barrier(0);
        __builtin_amdgcn_s_setprio(1);
        #pragma unroll
        for (int m = 0; m < 4; ++m)
            #pragma unroll
            for (int n = 0; n < 4; ++n)
                acc[m][n] = __builtin_amdgcn_mfma_f32_16x16x32_bf16(
                    af[m], bfr[n][0], acc[m][n], 0, 0, 0);
        __builtin_amdgcn_s_setprio(0);

        if (dostage) STAGE(curb ^ 1, kt + 1, 1);
        bf16x8 ag[4];
        #pragma unroll
        for (int m = 0; m < 4; ++m) {
            const int row = wr * 64 + m * 16 + lr;
            ag[m] = *(const bf16x8*)(Abase + row * 128 + (((4 + lk) ^ (row & 7)) << 4));
        }
        asm volatile("s_waitcnt lgkmcnt(0)" ::: "memory");
        __builtin_amdgcn_sched_barrier(0);
        __builtin_amdgcn_s_setprio(1);
        #pragma unroll
        for (int m = 0; m < 4; ++m)
            #pragma unroll
            for (int n = 0; n < 4; ++n)
                acc[m][n] = __builtin_amdgcn_mfma_f32_16x16x32_bf16(
                    ag[m], bfr[n][1], acc[m][n], 0, 0, 0);
        __builtin_amdgcn_s_setprio(0);
        __builtin_amdgcn_s_barrier();
    }

    #pragma unroll
    for (int m = 0; m < 4; ++m) {
        #pragma unroll
        for (int j = 0; j < 4; ++j) {
            const int row = bm + wr * 64 + m * 16 + lk * 4 + j;
            int b_ = 0, t_ = 0;
            if constexpr (EPI == EPI_QKV || EPI == EPI_KV) { b_ = row / p0; t_ = row % p0; }
            #pragma unroll
            for (int n = 0; n < 4; ++n) {
                const int col = bn + wc * 64 + n * 16 + lr;
                if constexpr (EPI == EPI_F32) {
                    float v = acc[m][n][j] + bias[col];
                    __builtin_nontemporal_store(v, &outF[(size_t)row * ldo + col]);
                } else if constexpr (EPI == EPI_ADD) {
                    float v = acc[m][n][j] + bias[col];
                    outF[(size_t)row * ldo + col] += v;
                } else if constexpr (EPI == EPI_GELU) {
                    float v = acc[m][n][j] + bias[col];
                    float u = 1.5957691216057308f * (v + 0.044715f * v * v * v);
                    float g_ = v / (1.0f + __expf(-u));
                    outB[(size_t)row * ldo + col] = (bf16_t)g_;
                } else if constexpr (EPI == EPI_QKV) {
                    float v = acc[m][n][j] + bias[col];
                    int h = col >> 6, d = col & 63;
                    outB[(((size_t)b_ * NH + h) * p0 + t_) * ND + d] = (bf16_t)v;
                } else if constexpr (EPI == EPI_KV) {
                    if (col < NC) {   // K half -> [B][H][NTK][D]
                        float v = acc[m][n][j] + bias[col];
                        int h = col >> 6, d = col & 63;
                        outB[(((size_t)b_ * NH + h) * NTK + t_) * ND + d] = (bf16_t)v;
                    } else {          // V half -> [B][H][D][NTK]
                        int c2_ = col - NC;
                        float v = acc[m][n][j] + bias2[c2_];
                        int h = c2_ >> 6, d = c2_ & 63;
                        outB2[(((size_t)b_ * NH + h) * ND + d) * NTK + t_] = (bf16_t)v;
                    }
                }
            }
        }
    }
}

// ---------------------------------------------------------------------------
// Legacy 128x128/BK=32 GEMM (only for tiny m2 GEMM).
// ---------------------------------------------------------------------------
template<int EPI>
__global__ __launch_bounds__(256) void gemm_bt(
    const bf16_t* __restrict__ A, const bf16_t* __restrict__ Bt,
    const float* __restrict__ bias, const float* __restrict__ bias2,
    float* __restrict__ outF, bf16_t* __restrict__ outB, bf16_t* __restrict__ outB2,
    int M, int N, int K, int p0, int ldo, int gm)
{
    __shared__ bf16_t lA[128 * 32];
    __shared__ bf16_t lB[128 * 32];
    const int tid = threadIdx.x;
    const int nwg = gridDim.x;
    const int bid = blockIdx.x;
    const int xcd = bid & 7, base = bid >> 3;
    const int qq = nwg >> 3, rr = nwg & 7;
    int wg = (xcd < rr ? xcd * (qq + 1) : rr * (qq + 1) + (xcd - rr) * qq) + base;
    const int nnt = N >> 7;
    const int gsz = gm * nnt;
    const int g = wg / gsz, r2 = wg - g * gsz;
    const int ntl = r2 / gm, mt = g * gm + (r2 - ntl * gm);
    const int bm = mt * 128, bn = ntl * 128;
    const bf16_t* Ab = A + (size_t)bm * K;
    const bf16_t* Bb = Bt + (size_t)bn * K;
    const int wave = tid >> 6, lane = tid & 63;
    const int wr = wave >> 1, wc = wave & 1;
    const int lr = lane & 15, lk = lane >> 4;
    f32x4 acc[4][4] = {};
    const int nk = K >> 5;
    const int c1 = tid, c2 = tid + 256;
    for (int kt = 0; kt < nk; ++kt) {
        __syncthreads();
        const bf16_t* Abk = Ab + kt * 32;
        const bf16_t* Bbk = Bb + kt * 32;
        GLOAD_LDS16(Abk + (size_t)(c1 >> 2) * K + (c1 & 3) * 8, (char*)lA + c1 * 16);
        GLOAD_LDS16(Abk + (size_t)(c2 >> 2) * K + (c2 & 3) * 8, (char*)lA + c2 * 16);
        GLOAD_LDS16(Bbk + (size_t)(c1 >> 2) * K + (c1 & 3) * 8, (char*)lB + c1 * 16);
        GLOAD_LDS16(Bbk + (size_t)(c2 >> 2) * K + (c2 & 3) * 8, (char*)lB + c2 * 16);
        __syncthreads();
        bf16x8 af[4], bfr[4];
        #pragma unroll
        for (int m = 0; m < 4; ++m)
            af[m] = *(const bf16x8*)&lA[(wr * 64 + m * 16 + lr) * 32 + lk * 8];
        #pragma unroll
        for (int n = 0; n < 4; ++n)
            bfr[n] = *(const bf16x8*)&lB[(wc * 64 + n * 16 + lr) * 32 + lk * 8];
        #pragma unroll
        for (int m = 0; m < 4; ++m)
            #pragma unroll
            for (int n = 0; n < 4; ++n)
                acc[m][n] = __builtin_amdgcn_mfma_f32_16x16x32_bf16(af[m], bfr[n], acc[m][n], 0, 0, 0);
    }
    #pragma unroll
    for (int m = 0; m < 4; ++m) {
        #pragma unroll
        for (int j = 0; j < 4; ++j) {
            const int row = bm + wr * 64 + m * 16 + lk * 4 + j;
            #pragma unroll
            for (int n = 0; n < 4; ++n) {
                const int col = bn + wc * 64 + n * 16 + lr;
                if constexpr (EPI == EPI_F32) {
                    float v = acc[m][n][j] + bias[col];
                    __builtin_nontemporal_store(v, &outF[(size_t)row * ldo + col]);
                }
            }
        }
    }
}

// ---------------------------------------------------------------------------
// Transpose+cast body + mega-kernel: head + mem + ALL 4 layers in ONE launch.
// ---------------------------------------------------------------------------
__device__ __forceinline__ void tc_body(
    const float* __restrict__ W, bf16_t* __restrict__ Wt,
    int K, int N, int k0, int n0, int t)
{
    __shared__ float tile[64][65];
    #pragma unroll
    for (int i = 0; i < 4; ++i) {
        const int idx = t + i * 256;
        const int r = idx >> 4, c4 = (idx & 15) << 2;
        const float4 v = *(const float4*)(W + (size_t)(k0 + r) * N + n0 + c4);
        tile[r][c4 + 0] = v.x; tile[r][c4 + 1] = v.y;
        tile[r][c4 + 2] = v.z; tile[r][c4 + 3] = v.w;
    }
    __syncthreads();
    #pragma unroll
    for (int i = 0; i < 4; ++i) {
        const int idx = t + i * 256;
        const int r = idx >> 4, c4 = (idx & 15) << 2;
        bf16x4 o = {(bf16_t)tile[c4 + 0][r], (bf16_t)tile[c4 + 1][r],
                    (bf16_t)tile[c4 + 2][r], (bf16_t)tile[c4 + 3][r]};
        *(bf16x4*)(Wt + (size_t)(n0 + r) * K + k0 + c4) = o;
    }
}

// grid: 8000 (head) + 256 (mem) + 4*3072 (layers) = 20544 blocks
__global__ __launch_bounds__(256) void transpose_all(
    const float* __restrict__ head_w, const float* __restrict__ mem_w,
    const float* __restrict__ Wq, const float* __restrict__ Wk,
    const float* __restrict__ Wv, const float* __restrict__ Wo,
    const float* __restrict__ W1, const float* __restrict__ W2,
    bf16_t* __restrict__ wthead, bf16_t* __restrict__ wtmem,
    bf16_t* __restrict__ wtq, bf16_t* __restrict__ wtkv,
    bf16_t* __restrict__ wto, bf16_t* __restrict__ wt1, bf16_t* __restrict__ wt2)
{
    const int bid = blockIdx.x;
    const float* W; bf16_t* Wt; int K, N, k0, n0;
    if (bid < 8000) {                  // head: K=NC, N=NV, 16 x 500 tiles
        K = NC; N = NV;
        k0 = (bid & 15) << 6; n0 = (bid >> 4) << 6;
        W = head_w; Wt = wthead;
    } else if (bid < 8256) {           // mem: K=NC, N=NC
        const int r = bid - 8000;
        K = NC; N = NC;
        k0 = (r & 15) << 6; n0 = (r >> 4) << 6;
        W = mem_w; Wt = wtmem;
    } else {
        const int r3 = bid - 8256;
        const int l = r3 / 3072;       // layer
        const int r0 = r3 - l * 3072;
        if (r0 < 1024) {               // Wq/Wk/Wv/Wo
            const int which = r0 >> 8, r = r0 & 255;
            K = NC; N = NC;
            k0 = (r & 15) << 6; n0 = (r >> 4) << 6;
            const size_t lw = (size_t)l * NC * NC;
            W  = (which == 0) ? Wq + lw : (which == 1) ? Wk + lw
               : (which == 2) ? Wv + lw : Wo + lw;
            Wt = (which == 0) ? (wtq + lw) : (which == 1) ? (wtkv + (size_t)l * 2 * NC * NC)
               : (which == 2) ? (wtkv + (size_t)l * 2 * NC * NC + (size_t)NC * NC)
               : (wto + lw);
        } else if (r0 < 2048) {        // W1: K=NC, N=4NC
            const int r = r0 - 1024;
            K = NC; N = 4 * NC;
            k0 = (r & 15) << 6; n0 = (r >> 4) << 6;
            W = W1 + (size_t)l * NC * 4 * NC; Wt = wt1 + (size_t)l * NC * 4 * NC;
        } else {                       // W2: K=4NC, N=NC
            const int r = r0 - 2048;
            K = 4 * NC; N = NC;
            k0 = (r & 63) << 6; n0 = (r >> 6) << 6;
            W = W2 + (size_t)l * 4 * NC * NC; Wt = wt2 + (size_t)l * 4 * NC * NC;
        }
    }
    tc_body(W, Wt, K, N, k0, n0, threadIdx.x);
}

// ---------------------------------------------------------------------------
// LayerNorm over C=1024. MODE 0/1/3 as before.
// ---------------------------------------------------------------------------
template<int MODE>
__global__ __launch_bounds__(256) void ln_row(
    const float* __restrict__ X, const float* __restrict__ sw,
    const float* __restrict__ bw, float* __restrict__ outF,
    bf16_t* __restrict__ outB, bf16_t* __restrict__ outB2)
{
    const int row = blockIdx.x;
    const int t = threadIdx.x;
    const float4 v = ((const float4*)(X + (size_t)row * NC))[t];
    float s1 = v.x + v.y + v.z + v.w;
    float s2 = v.x * v.x + v.y * v.y + v.z * v.z + v.w * v.w;
    #pragma unroll
    for (int off = 32; off > 0; off >>= 1) { s1 += __shfl_xor(s1, off); s2 += __shfl_xor(s2, off); }
    __shared__ float rs1[4], rs2[4];
    if ((t & 63) == 0) { rs1[t >> 6] = s1; rs2[t >> 6] = s2; }
    __syncthreads();
    s1 = rs1[0] + rs1[1] + rs1[2] + rs1[3];
    s2 = rs2[0] + rs2[1] + rs2[2] + rs2[3];
    const float mu = s1 * (1.0f / NC);
    const float var = s2 * (1.0f / NC) - mu * mu;
    const float rstd = rsqrtf(var + 1e-6f);
    const int c = t * 4;
    const float4 sv = ((const float4*)sw)[t];
    const float4 bv = ((const float4*)bw)[t];
    float y0 = (v.x - mu) * rstd * sv.x + bv.x;
    float y1 = (v.y - mu) * rstd * sv.y + bv.y;
    float y2 = (v.z - mu) * rstd * sv.z + bv.z;
    float y3 = (v.w - mu) * rstd * sv.w + bv.w;
    size_t dst;
    if constexpr (MODE == 1) dst = ((size_t)(row / NO) * NTK + (row % NO)) * NC + c;
    else dst = (size_t)row * NC + c;
    bf16x4 o = {(bf16_t)y0, (bf16_t)y1, (bf16_t)y2, (bf16_t)y3};
    *(bf16x4*)(outB + dst) = o;
    if constexpr (MODE == 3) {
        const int b_ = row >> 10, t_ = row & 1023;
        bf16x4 o2 = {(bf16_t)v.x, (bf16_t)v.y, (bf16_t)v.z, (bf16_t)v.w};
        *(bf16x4*)(outB2 + ((size_t)b_ * NTK + NO + t_) * NC + c) = o2;
    }
}

// ---------------------------------------------------------------------------
// Final LN fused with mask-cast + new_mem extraction.
// ---------------------------------------------------------------------------
__global__ __launch_bounds__(256) void ln_final(
    const float* __restrict__ X, const float* __restrict__ sw,
    const float* __restrict__ bw, const int* __restrict__ tokens,
    bf16_t* __restrict__ xm, float* __restrict__ outMem)
{
    const int row = blockIdx.x;
    const int t = threadIdx.x;
    const float4 v = ((const float4*)(X + (size_t)row * NC))[t];
    float s1 = v.x + v.y + v.z + v.w;
    float s2 = v.x * v.x + v.y * v.y + v.z * v.z + v.w * v.w;
    #pragma unroll
    for (int off = 32; off > 0; off >>= 1) { s1 += __shfl_xor(s1, off); s2 += __shfl_xor(s2, off); }
    __shared__ float rs1[4], rs2[4];
    if ((t & 63) == 0) { rs1[t >> 6] = s1; rs2[t >> 6] = s2; }
    __syncthreads();
    s1 = rs1[0] + rs1[1] + rs1[2] + rs1[3];
    s2 = rs2[0] + rs2[1] + rs2[2] + rs2[3];
    const float mu = s1 * (1.0f / NC);
    const float var = s2 * (1.0f / NC) - mu * mu;
    const float rstd = rsqrtf(var + 1e-6f);
    const int c = t * 4;
    const float4 sv = ((const float4*)sw)[t];
    const float4 bv = ((const float4*)bw)[t];
    float y0 = (v.x - mu) * rstd * sv.x + bv.x;
    float y1 = (v.y - mu) * rstd * sv.y + bv.y;
    float y2 = (v.z - mu) * rstd * sv.z + bv.z;
    float y3 = (v.w - mu) * rstd * sv.w + bv.w;
    const bool ok = tokens[row] != 0;
    bf16x4 o;
    if (ok) { o = (bf16x4){(bf16_t)y0, (bf16_t)y1, (bf16_t)y2, (bf16_t)y3}; }
    else    { o = (bf16x4){(bf16_t)0.f, (bf16_t)0.f, (bf16_t)0.f, (bf16_t)0.f}; }
    *(bf16x4*)(xm + (size_t)row * NC + c) = o;
    const int b_ = row >> 10, t_ = row & 1023;
    if (t_ >= NT - NO) {
        float4 f; f.x = y0; f.y = y1; f.z = y2; f.w = y3;
        *(float4*)(outMem + ((size_t)b_ * NO + (t_ - (NT - NO))) * NC + c) = f;
    }
}

// ---------------------------------------------------------------------------
// Flash attention: 32 q-rows per wave (2 subtiles sharing K/V fragment
// loads), 4 waves/block, no barriers, 64-key tiles, LPT y-order.
// ---------------------------------------------------------------------------
__global__ __launch_bounds__(256) void attn_kernel(
    const bf16_t* __restrict__ Q, const bf16_t* __restrict__ Kb,
    const bf16_t* __restrict__ Vt, const int* __restrict__ tokens,
    bf16_t* __restrict__ Ob)
{
    const int bh = blockIdx.x;
    const int b = bh >> 4, h = bh & 15;
    const int w = threadIdx.x >> 6;
    const int lane = threadIdx.x & 63;
    const int yt = gridDim.y - 1 - blockIdx.y;   // LPT: long tiles first
    const int q0 = (yt << 7) + (w << 5);
    const int lr = lane & 15, lk = lane >> 4;
    const bf16_t* Qp = Q + ((size_t)bh * NT + q0) * ND;
    bf16x8 qf[2][2];
    #pragma unroll
    for (int qs = 0; qs < 2; ++qs) {
        qf[qs][0] = *(const bf16x8*)(Qp + (qs * 16 + lr) * ND + lk * 8);
        qf[qs][1] = *(const bf16x8*)(Qp + (qs * 16 + lr) * ND + 32 + lk * 8);
    }
    const bf16_t* Kbase = Kb + (size_t)bh * NTK * ND;
    const bf16_t* Vbase = Vt + (size_t)bh * ND * NTK;
    const int* tokb = tokens + b * NT;
    float mrow[2][4] = {{-1e30f, -1e30f, -1e30f, -1e30f}, {-1e30f, -1e30f, -1e30f, -1e30f}};
    float lsum[2][4] = {};
    f32x4 acc[2][4] = {};
    __shared__ bf16_t pb[4][2][16 * 64];
    const int kmax = NO + q0 + 32;
    for (int k0 = 0; k0 < kmax; k0 += 64) {
        f32x4 st[2][4] = {};
        __builtin_amdgcn_s_setprio(1);
        #pragma unroll
        for (int nt = 0; nt < 4; ++nt) {
            const bf16_t* Kp = Kbase + (size_t)(k0 + nt * 16 + lr) * ND + lk * 8;
            bf16x8 kf0 = *(const bf16x8*)(Kp);
            bf16x8 kf1 = *(const bf16x8*)(Kp + 32);
            #pragma unroll
            for (int qs = 0; qs < 2; ++qs) {
                st[qs][nt] = __builtin_amdgcn_mfma_f32_16x16x32_bf16(qf[qs][0], kf0, st[qs][nt], 0, 0, 0);
                st[qs][nt] = __builtin_amdgcn_mfma_f32_16x16x32_bf16(qf[qs][1], kf1, st[qs][nt], 0, 0, 0);
            }
        }
        __builtin_amdgcn_s_setprio(0);
        #pragma unroll
        for (int qs = 0; qs < 2; ++qs) {
            char* pbq = (char*)pb[w][qs];
            float sc[4][4];
            float tmax[4] = {-1e30f, -1e30f, -1e30f, -1e30f};
            #pragma unroll
            for (int nt = 0; nt < 4; ++nt) {
                const int key = k0 + nt * 16 + lr;
                const int kt = key - NO;
                const int kts = kt < 0 ? 0 : kt;
                const bool keyok = (kt < 0) | (tokb[kts] != 0);
                #pragma unroll
                for (int j = 0; j < 4; ++j) {
                    const int qrow = q0 + qs * 16 + lk * 4 + j;
                    const bool ok = keyok && (kt <= qrow);
                    const float s = ok ? st[qs][nt][j] * 0.125f : -1e9f;
                    sc[nt][j] = s;
                    tmax[j] = fmaxf(tmax[j], s);
                }
            }
            #pragma unroll
            for (int off = 1; off < 16; off <<= 1)
                #pragma unroll
                for (int j = 0; j < 4; ++j) tmax[j] = fmaxf(tmax[j], __shfl_xor(tmax[j], off));
            float resc[4], p[4][4], psum[4] = {0.f, 0.f, 0.f, 0.f};
            #pragma unroll
            for (int j = 0; j < 4; ++j) {
                const float mnew = fmaxf(mrow[qs][j], tmax[j]);
                resc[j] = __expf(mrow[qs][j] - mnew);
                mrow[qs][j] = mnew;
            }
            #pragma unroll
            for (int nt = 0; nt < 4; ++nt)
                #pragma unroll
                for (int j = 0; j < 4; ++j) { p[nt][j] = __expf(sc[nt][j] - mrow[qs][j]); psum[j] += p[nt][j]; }
            #pragma unroll
            for (int off = 1; off < 16; off <<= 1)
                #pragma unroll
                for (int j = 0; j < 4; ++j) psum[j] += __shfl_xor(psum[j], off);
            #pragma unroll
            for (int j = 0; j < 4; ++j) lsum[qs][j] = lsum[qs][j] * resc[j] + psum[j];
            #pragma unroll
            for (int dt = 0; dt < 4; ++dt)
                #pragma unroll
                for (int j = 0; j < 4; ++j) acc[qs][dt][j] *= resc[j];
            #pragma unroll
            for (int nt = 0; nt < 4; ++nt)
                #pragma unroll
                for (int j = 0; j < 4; ++j) {
                    const int row = lk * 4 + j;
                    const int byt = (row << 7) + ((((nt << 4) + lr) << 1) ^ ((row & 7) << 4));
                    *(bf16_t*)(pbq + byt) = (bf16_t)p[nt][j];
                }
        }
        const int swz = (lr & 7) << 4;
        bf16x8 pa[2][2];
        #pragma unroll
        for (int qs = 0; qs < 2; ++qs) {
            const char* pbq = (const char*)pb[w][qs];
            pa[qs][0] = *(const bf16x8*)(pbq + ((lr << 7) + (((lk << 4)) ^ swz)));
            pa[qs][1] = *(const bf16x8*)(pbq + ((lr << 7) + ((64 + (lk << 4)) ^ swz)));
        }
        __builtin_amdgcn_s_setprio(1);
        #pragma unroll
        for (int dt = 0; dt < 4; ++dt) {
            const bf16_t* Vp = Vbase + (size_t)(dt * 16 + lr) * NTK + k0 + lk * 8;
            bf16x8 vf0 = *(const bf16x8*)(Vp);
            bf16x8 vf1 = *(const bf16x8*)(Vp + 32);
            #pragma unroll
            for (int qs = 0; qs < 2; ++qs) {
                acc[qs][dt] = __builtin_amdgcn_mfma_f32_16x16x32_bf16(pa[qs][0], vf0, acc[qs][dt], 0, 0, 0);
                acc[qs][dt] = __builtin_amdgcn_mfma_f32_16x16x32_bf16(pa[qs][1], vf1, acc[qs][dt], 0, 0, 0);
            }
        }
        __builtin_amdgcn_s_setprio(0);
    }
    #pragma unroll
    for (int qs = 0; qs < 2; ++qs)
        #pragma unroll
        for (int dt = 0; dt < 4; ++dt)
            #pragma unroll
            for (int j = 0; j < 4; ++j)
                Ob[((size_t)b * NT + q0 + qs * 16 + lk * 4 + j) * NC + h * ND + dt * 16 + lr] =
                    (bf16_t)(acc[qs][dt][j] / lsum[qs][j]);
}

// ---------------------------------------------------------------------------
// Small kernels
// ---------------------------------------------------------------------------
__global__ __launch_bounds__(256) void sum_proj_kernel(
    const float* __restrict__ ssum, const float* __restrict__ sumw,
    const float* __restrict__ alpha, float* __restrict__ add)
{
    const int b = blockIdx.y;
    const int c = blockIdx.x * 256 + threadIdx.x;
    float a = 0.f;
    for (int k = 0; k < NC; ++k) a += ssum[b * NC + k] * sumw[(size_t)k * NC + c];
    add[b * NC + c] = a * sigmoidf_(alpha[c]);
}

__global__ __launch_bounds__(256) void embed_kernel(
    const int* __restrict__ tokens, const int* __restrict__ posoff,
    const float* __restrict__ tokw, const float* __restrict__ posw,
    const float* __restrict__ add, float* __restrict__ X)
{
    const int bt = blockIdx.x;
    const int b = bt >> 10, t = bt & 1023;
    const int c = threadIdx.x * 4;
    const int tok = tokens[bt];
    int p = t + posoff[0];
    p = p < 0 ? 0 : (p > NS - 1 ? NS - 1 : p);
    const float4 tv = *(const float4*)(tokw + (size_t)tok * NC + c);
    const float4 pv = *(const float4*)(posw + (size_t)p * NC + c);
    const float4 av = *(const float4*)(add + b * NC + c);
    float4 o;
    o.x = tv.x + pv.x + av.x; o.y = tv.y + pv.y + av.y;
    o.z = tv.z + pv.z + av.z; o.w = tv.w + pv.w + av.w;
    *(float4*)(X + (size_t)bt * NC + c) = o;
}

__global__ __launch_bounds__(256) void cast_f32_bf16_kernel(
    const float* __restrict__ in, bf16_t* __restrict__ out)
{
    const size_t i = ((size_t)blockIdx.x * 256 + threadIdx.x) * 4;
    const float4 v = *(const float4*)(in + i);
    bf16x4 o = {(bf16_t)v.x, (bf16_t)v.y, (bf16_t)v.z, (bf16_t)v.w};
    *(bf16x4*)(out + i) = o;
}

__global__ __launch_bounds__(256) void sumpart_kernel(
    const bf16_t* __restrict__ XM, float* __restrict__ sbuf)
{
    const int b = blockIdx.z;
    const int c = blockIdx.x * 256 + threadIdx.x;
    const int t0 = blockIdx.y * 64;
    float a = 0.f;
    for (int t = t0; t < t0 + 64; ++t)
        a += (float)XM[((size_t)b * NT + t) * NC + c];
    atomicAdd(&sbuf[b * NC + c], a);
}

__global__ __launch_bounds__(256) void ssum_out_kernel(
    const float* __restrict__ sbuf, const int* __restrict__ tokens,
    const float* __restrict__ ssum, const float* __restrict__ lamp, float* __restrict__ out)
{
    const int b = blockIdx.y;
    const int c = blockIdx.x * 256 + threadIdx.x;
    int cnt = 0;
    for (int t = 0; t < NT; ++t) cnt += (tokens[b * NT + t] != 0);
    const float summary = sbuf[b * NC + c] / ((float)cnt + 1e-6f);
    const float lam = sigmoidf_(lamp[c]);
    out[b * NC + c] = ssum[b * NC + c] * lam + summary * (1.0f - lam);
}

// ---------------------------------------------------------------------------
extern "C" void kernel_launch(void* const* d_in, const int* in_sizes, int n_in,
                              void* d_out, int out_size, void* d_ws, size_t ws_size,
                              hipStream_t stream)
{
    (void)in_sizes; (void)n_in; (void)out_size; (void)ws_size;
    const int*   tokens   = (const int*)d_in[0];
    const int*   posoff   = (const int*)d_in[1];
    const float* mem      = (const float*)d_in[2];
    const float* ssum     = (const float*)d_in[3];
    const float* tok_emb  = (const float*)d_in[4];
    const float* pos_emb  = (const float*)d_in[5];
    const float* mem_w    = (const float*)d_in[6];
    const float* mem_b    = (const float*)d_in[7];
    const float* memln_s  = (const float*)d_in[8];
    const float* memln_b  = (const float*)d_in[9];
    const float* alpha_p  = (const float*)d_in[10];
    const float* sum_w    = (const float*)d_in[11];
    const float* ln1_s    = (const float*)d_in[12];
    const float* ln1_b    = (const float*)d_in[13];
    const float* Wq       = (const float*)d_in[14];
    const float* bq       = (const float*)d_in[15];
    const float* Wk       = (const float*)d_in[16];
    const float* bk       = (const float*)d_in[17];
    const float* Wv       = (const float*)d_in[18];
    const float* bv       = (const float*)d_in[19];
    const float* Wo       = (const float*)d_in[20];
    const float* bo       = (const float*)d_in[21];
    const float* ln2_s    = (const float*)d_in[22];
    const float* ln2_b    = (const float*)d_in[23];
    const float* W1       = (const float*)d_in[24];
    const float* b1       = (const float*)d_in[25];
    const float* W2       = (const float*)d_in[26];
    const float* b2       = (const float*)d_in[27];
    const float* fln_s    = (const float*)d_in[28];
    const float* fln_b    = (const float*)d_in[29];
    const float* head_w   = (const float*)d_in[30];
    const float* head_b   = (const float*)d_in[31];
    const float* lam_p    = (const float*)d_in[32];

    float* out_mem    = (float*)d_out;                          // B*O*C
    float* out_ssum   = out_mem + (size_t)NB * NO * NC;         // B*C
    float* out_logits = out_ssum + (size_t)NB * NC;             // B*T*V

    char* wp = (char*)d_ws;
    auto alloc = [&](size_t bytes) { char* p = wp; wp += (bytes + 255) & ~(size_t)255; return p; };
    bf16_t* wt_head = (bf16_t*)alloc((size_t)NV * NC * 2);
    bf16_t* wt_mem  = (bf16_t*)alloc((size_t)NC * NC * 2);
    bf16_t* wt_q    = (bf16_t*)alloc((size_t)NL * NC * NC * 2);
    bf16_t* wt_kv   = (bf16_t*)alloc((size_t)NL * 2 * NC * NC * 2);
    bf16_t* wt_o    = (bf16_t*)alloc((size_t)NL * NC * NC * 2);
    bf16_t* wt_1    = (bf16_t*)alloc((size_t)NL * NC * 4 * NC * 2);
    bf16_t* wt_2    = (bf16_t*)alloc((size_t)NL * NC * 4 * NC * 2);
    float*  xbuf    = (float*)alloc((size_t)NB * NT * NC * 4);
    bf16_t* hbuf    = (bf16_t*)alloc((size_t)NB * NT * NC * 2);
    bf16_t* kvbuf   = (bf16_t*)alloc((size_t)NB * NTK * NC * 2);
    bf16_t* qbuf    = (bf16_t*)alloc((size_t)NB * NT * NC * 2);
    bf16_t* kbuf    = (bf16_t*)alloc((size_t)NB * NTK * NC * 2);
    bf16_t* vtbuf   = (bf16_t*)alloc((size_t)NB * NTK * NC * 2);
    bf16_t* obuf    = (bf16_t*)alloc((size_t)NB * NT * NC * 2);
    bf16_t* midbuf  = (bf16_t*)alloc((size_t)NB * NT * 4 * NC * 2);
    bf16_t* xmbuf   = (bf16_t*)alloc((size_t)NB * NT * NC * 2);
    bf16_t* membf   = (bf16_t*)alloc((size_t)NB * NO * NC * 2);
    float*  m2f     = (float*)alloc((size_t)NB * NO * NC * 4);
    float*  addb    = (float*)alloc((size_t)NB * NC * 4);
    float*  sbuf    = (float*)alloc((size_t)NB * NC * 4);

    hipMemsetAsync(sbuf, 0, (size_t)NB * NC * 4, stream);

    // ALL weight transposes in one launch (no dependency on anything else)
    transpose_all<<<20544, 256, 0, stream>>>(
        head_w, mem_w, Wq, Wk, Wv, Wo, W1, W2,
        wt_head, wt_mem, wt_q, wt_kv, wt_o, wt_1, wt_2);

    // m2 = LN(mem @ mem_w + mem_b) -> kv rows [0,O)
    cast_f32_bf16_kernel<<<(NB * NO * NC) / 1024, 256, 0, stream>>>(mem, membf);
    gemm_bt<EPI_F32><<<32, 256, 0, stream>>>(
        membf, wt_mem, mem_b, nullptr, m2f, nullptr, nullptr, NB * NO, NC, NC, 0, NC, 4);
    ln_row<1><<<NB * NO, 256, 0, stream>>>(m2f, memln_s, memln_b, nullptr, kvbuf, nullptr);

    // x = tok_emb[tokens] + pos_emb + (ssum @ sum_w)*sigmoid(alpha)
    sum_proj_kernel<<<dim3(NC / 256, NB), 256, 0, stream>>>(ssum, sum_w, alpha_p, addb);
    embed_kernel<<<NB * NT, 256, 0, stream>>>(tokens, posoff, tok_emb, pos_emb, addb, xbuf);

    for (int i = 0; i < NL; ++i) {
        const size_t lw = (size_t)i * NC * NC;
        // ln1 + x->kv cast fused
        ln_row<3><<<NB * NT, 256, 0, stream>>>(xbuf, ln1_s + i * NC, ln1_b + i * NC, nullptr, hbuf, kvbuf);

        gemm128<EPI_QKV><<<256, 256, 0, stream>>>(
            hbuf, wt_q + lw, bq + i * NC, nullptr, nullptr, qbuf, nullptr, NB * NT, NC, NC, NT, 0, 8);
        gemm128<EPI_KV><<<576, 256, 0, stream>>>(
            kvbuf, wt_kv + (size_t)i * 2 * NC * NC, bk + i * NC, bv + i * NC,
            nullptr, kbuf, vtbuf, NB * NTK, 2 * NC, NC, NTK, 0, 6);

        attn_kernel<<<dim3(NB * NH, NT / 128), 256, 0, stream>>>(qbuf, kbuf, vtbuf, tokens, obuf);

        gemm128<EPI_ADD><<<256, 256, 0, stream>>>(
            obuf, wt_o + lw, bo + i * NC, nullptr, xbuf, nullptr, nullptr, NB * NT, NC, NC, 0, NC, 8);

        ln_row<0><<<NB * NT, 256, 0, stream>>>(xbuf, ln2_s + i * NC, ln2_b + i * NC, nullptr, hbuf, nullptr);
        // FFN1: 256^2 engine (GELU epilogue)
        gemm8p<1><<<256, 512, 0, stream>>>(
            hbuf, wt_1 + (size_t)i * NC * 4 * NC, b1 + (size_t)i * 4 * NC, nullptr, midbuf,
            NB * NT, 4 * NC, NC, 4 * NC, 4);
        // FFN2: round-10 proven config (EPI_ADD, ks=1)
        gemm128<EPI_ADD><<<256, 256, 0, stream>>>(
            midbuf, wt_2 + (size_t)i * 4 * NC * NC, b2 + i * NC, nullptr, xbuf, nullptr, nullptr,
            NB * NT, NC, 4 * NC, 0, NC, 8);
    }

    // final LN fused with mask-cast + new_mem extraction
    ln_final<<<NB * NT, 256, 0, stream>>>(xbuf, fln_s, fln_b, tokens, xmbuf, out_mem);
    sumpart_kernel<<<dim3(NC / 256, NT / 64, NB), 256, 0, stream>>>(xmbuf, sbuf);
    ssum_out_kernel<<<dim3(NC / 256, NB), 256, 0, stream>>>(sbuf, tokens, ssum, lam_p, out_ssum);
    // head: 256^2 engine
    gemm8p<0><<<2000, 512, 0, stream>>>(
        xmbuf, wt_head, head_b, out_logits, nullptr, NB * NT, NV, NC, NV, 4);
}

// Round 14
// 1669.901 us; speedup vs baseline: 1.0926x; 1.0926x over previous
//
#include <hip/hip_runtime.h>
#include <hip/hip_bf16.h>

typedef __bf16 bf16_t;
typedef __bf16 bf16x8 __attribute__((ext_vector_type(8)));
typedef __bf16 bf16x4 __attribute__((ext_vector_type(4)));
typedef float f32x4 __attribute__((ext_vector_type(4)));

#define NB 4
#define NT 1024
#define NO 128
#define NC 1024
#define NH 16
#define NL 4
#define NV 32000
#define NS 4096
#define ND 64
#define NTK (NO + NT)   // 1152

#define GLOAD_LDS16(g, l) __builtin_amdgcn_global_load_lds( \
    (__attribute__((address_space(1))) void*)(g), \
    (__attribute__((address_space(3))) void*)(l), 16, 0, 0)

__device__ __forceinline__ float sigmoidf_(float x) { return 1.0f / (1.0f + __expf(-x)); }

#define EPI_F32  0
#define EPI_ADD  1
#define EPI_GELU 2
#define EPI_QKV  3
#define EPI_KV   4

// ---------------------------------------------------------------------------
// 8-wave 256x256 GEMM (round-6 engine): BK=64, 512 thr, double-buffered
// 128KB LDS, counted vmcnt, raw s_barrier, XOR swizzle, fragment reuse.
// EPI 0: f32 nontemporal; 1: GELU->bf16.
// ---------------------------------------------------------------------------
template<int EPI>
__global__ __launch_bounds__(512) void gemm8p(
    const bf16_t* __restrict__ A, const bf16_t* __restrict__ Bt,
    const float* __restrict__ bias, float* __restrict__ outF,
    bf16_t* __restrict__ outB, int M, int N, int K, int ldo, int gm)
{
    __shared__ bf16_t sm[65536];
    const int tid = threadIdx.x;
    const int w = tid >> 6, lane = tid & 63;
    const int wr = w >> 2, wc = w & 3;
    const int lr = lane & 15, lk = lane >> 4;
    const int nwg = gridDim.x;
    const int bid = blockIdx.x;
    const int xcd = bid & 7, base = bid >> 3;
    const int qq = nwg >> 3, rr = nwg & 7;
    int wg = (xcd < rr ? xcd * (qq + 1) : rr * (qq + 1) + (xcd - rr) * qq) + base;
    const int nnt = N >> 8;
    const int gsz = gm * nnt;
    const int g = wg / gsz, r2 = wg - g * gsz;
    const int ntl = r2 / gm, mt = g * gm + (r2 - ntl * gm);
    const int bm = mt << 8, bn = ntl << 8;
    const bf16_t* Ab = A + (size_t)bm * K;
    const bf16_t* Bb = Bt + (size_t)bn * K;
    const int srow = tid >> 3;
    const int scol = ((tid & 7) ^ (srow & 7)) << 3;
    const int nk = K >> 6;
    f32x4 acc[8][4] = {};

    auto STAGE = [&](int b, int kt, int h) {
        const bf16_t* gsrc = (h < 2) ? Ab : Bb;
        const int half = h & 1;
        char* lbase = (char*)(sm + ((h < 2) ? 0 : 32768) + b * 16384 + half * 8192);
        #pragma unroll
        for (int i = 0; i < 2; ++i) {
            GLOAD_LDS16(gsrc + (size_t)(half * 128 + i * 64 + srow) * K + kt * 64 + scol,
                        lbase + (i * 512 + tid) * 16);
        }
    };

    #pragma unroll
    for (int h = 0; h < 4; ++h) STAGE(0, 0, h);
    asm volatile("s_waitcnt vmcnt(0)" ::: "memory");
    __builtin_amdgcn_s_barrier();

    for (int kt = 0; kt < nk; ++kt) {
        const int curb = kt & 1;
        const bool dostage = (kt + 1) < nk;
        const char* Abase = (const char*)(sm + curb * 16384);
        const char* Bbase = (const char*)(sm + 32768 + curb * 16384);

        if (dostage) {
            STAGE(curb ^ 1, kt + 1, 0);
            STAGE(curb ^ 1, kt + 1, 1);
            asm volatile("s_waitcnt vmcnt(4)" ::: "memory");
        } else {
            asm volatile("s_waitcnt vmcnt(0)" ::: "memory");
        }
        __builtin_amdgcn_s_barrier();

        bf16x8 bfr[4][2];
        #pragma unroll
        for (int n = 0; n < 4; ++n)
            #pragma unroll
            for (int ks = 0; ks < 2; ++ks) {
                const int row = wc * 64 + n * 16 + lr;
                bfr[n][ks] = *(const bf16x8*)(Bbase + row * 128 + ((((ks << 2) + lk) ^ (row & 7)) << 4));
            }
        bf16x8 af[4][2];
        #pragma unroll
        for (int m = 0; m < 4; ++m)
            #pragma unroll
            for (int ks = 0; ks < 2; ++ks) {
                const int row = wr * 128 + m * 16 + lr;
                af[m][ks] = *(const bf16x8*)(Abase + row * 128 + ((((ks << 2) + lk) ^ (row & 7)) << 4));
            }
        asm volatile("s_waitcnt lgkmcnt(0)" ::: "memory");
        __builtin_amdgcn_sched_barrier(0);
        __builtin_amdgcn_s_setprio(1);
        #pragma unroll
        for (int m = 0; m < 4; ++m)
            #pragma unroll
            for (int n = 0; n < 4; ++n)
                #pragma unroll
                for (int ks = 0; ks < 2; ++ks)
                    acc[m][n] = __builtin_amdgcn_mfma_f32_16x16x32_bf16(
                        af[m][ks], bfr[n][ks], acc[m][n], 0, 0, 0);
        __builtin_amdgcn_s_setprio(0);

        if (dostage) {
            STAGE(curb ^ 1, kt + 1, 2);
            STAGE(curb ^ 1, kt + 1, 3);
        }
        bf16x8 ag[4][2];
        #pragma unroll
        for (int m = 0; m < 4; ++m)
            #pragma unroll
            for (int ks = 0; ks < 2; ++ks) {
                const int row = wr * 128 + 64 + m * 16 + lr;
                ag[m][ks] = *(const bf16x8*)(Abase + row * 128 + ((((ks << 2) + lk) ^ (row & 7)) << 4));
            }
        asm volatile("s_waitcnt lgkmcnt(0)" ::: "memory");
        __builtin_amdgcn_sched_barrier(0);
        __builtin_amdgcn_s_setprio(1);
        #pragma unroll
        for (int m = 0; m < 4; ++m)
            #pragma unroll
            for (int n = 0; n < 4; ++n)
                #pragma unroll
                for (int ks = 0; ks < 2; ++ks)
                    acc[4 + m][n] = __builtin_amdgcn_mfma_f32_16x16x32_bf16(
                        ag[m][ks], bfr[n][ks], acc[4 + m][n], 0, 0, 0);
        __builtin_amdgcn_s_setprio(0);
        __builtin_amdgcn_s_barrier();
    }

    float bv4[4];
    #pragma unroll
    for (int n = 0; n < 4; ++n) bv4[n] = bias[bn + wc * 64 + n * 16 + lr];
    #pragma unroll
    for (int m = 0; m < 8; ++m) {
        #pragma unroll
        for (int j = 0; j < 4; ++j) {
            const int row = bm + wr * 128 + m * 16 + lk * 4 + j;
            #pragma unroll
            for (int n = 0; n < 4; ++n) {
                const int col = bn + wc * 64 + n * 16 + lr;
                float v = acc[m][n][j] + bv4[n];
                if constexpr (EPI == 0) {
                    __builtin_nontemporal_store(v, &outF[(size_t)row * ldo + col]);
                } else {
                    float u = 1.5957691216057308f * (v + 0.044715f * v * v * v);
                    float g_ = v / (1.0f + __expf(-u));
                    outB[(size_t)row * ldo + col] = (bf16_t)g_;
                }
            }
        }
    }
}

// ---------------------------------------------------------------------------
// 4-wave 128x128 GEMM body (round-6 schedule): BK=64, 256 thr, 64 KB LDS,
// counted vmcnt(4), XOR swizzle, B-frags held across both ks-phases.
// Shared by gemm128 kernel and qkv_fused.
// ---------------------------------------------------------------------------
template<int EPI>
__device__ __forceinline__ void gemm128_body(
    bf16_t* sm, int bid, int nwg,
    const bf16_t* __restrict__ A, const bf16_t* __restrict__ Bt,
    const float* __restrict__ bias, const float* __restrict__ bias2,
    float* __restrict__ outF, bf16_t* __restrict__ outB, bf16_t* __restrict__ outB2,
    int M, int N, int K, int p0, int ldo, int gm)
{
    char* smb = (char*)sm;
    const int tid = threadIdx.x;
    const int w = tid >> 6, lane = tid & 63;
    const int wr = w >> 1, wc = w & 1;
    const int lr = lane & 15, lk = lane >> 4;
    const int xcd = bid & 7, base = bid >> 3;
    const int qq = nwg >> 3, rr = nwg & 7;
    int wg = (xcd < rr ? xcd * (qq + 1) : rr * (qq + 1) + (xcd - rr) * qq) + base;
    const int nnt = N >> 7;
    const int gsz = gm * nnt;
    const int g = wg / gsz, r2 = wg - g * gsz;
    const int ntl = r2 / gm, mt = g * gm + (r2 - ntl * gm);
    const int bm = mt << 7, bn = ntl << 7;
    const bf16_t* Ab = A + (size_t)bm * K;
    const bf16_t* Bb = Bt + (size_t)bn * K;
    const int srow = tid >> 3;
    const int scol = ((tid & 7) ^ (srow & 7)) << 3;
    const int nk = K >> 6;
    f32x4 acc[4][4] = {};

    auto STAGE = [&](int b, int kt, int h) {
        const bf16_t* gsrc = h ? Bb : Ab;
        char* lbase = smb + h * 32768 + b * 16384;
        #pragma unroll
        for (int i = 0; i < 4; ++i) {
            GLOAD_LDS16(gsrc + (size_t)(i * 32 + srow) * K + kt * 64 + scol,
                        lbase + (i * 256 + tid) * 16);
        }
    };

    STAGE(0, 0, 0); STAGE(0, 0, 1);
    asm volatile("s_waitcnt vmcnt(0)" ::: "memory");
    __builtin_amdgcn_s_barrier();

    for (int kt = 0; kt < nk; ++kt) {
        const int curb = kt & 1;
        const bool dostage = (kt + 1) < nk;
        const char* Abase = smb + curb * 16384;
        const char* Bbase = smb + 32768 + curb * 16384;

        if (dostage) {
            STAGE(curb ^ 1, kt + 1, 0);
            asm volatile("s_waitcnt vmcnt(4)" ::: "memory");
        } else {
            asm volatile("s_waitcnt vmcnt(0)" ::: "memory");
        }
        __builtin_amdgcn_s_barrier();

        bf16x8 bfr[4][2];
        #pragma unroll
        for (int n = 0; n < 4; ++n)
            #pragma unroll
            for (int ks_ = 0; ks_ < 2; ++ks_) {
                const int row = wc * 64 + n * 16 + lr;
                bfr[n][ks_] = *(const bf16x8*)(Bbase + row * 128 + ((((ks_ << 2) + lk) ^ (row & 7)) << 4));
            }
        bf16x8 af[4];
        #pragma unroll
        for (int m = 0; m < 4; ++m) {
            const int row = wr * 64 + m * 16 + lr;
            af[m] = *(const bf16x8*)(Abase + row * 128 + (((lk) ^ (row & 7)) << 4));
        }
        asm volatile("s_waitcnt lgkmcnt(0)" ::: "memory");
        __builtin_amdgcn_sched_barrier(0);
        __builtin_amdgcn_s_setprio(1);
        #pragma unroll
        for (int m = 0; m < 4; ++m)
            #pragma unroll
            for (int n = 0; n < 4; ++n)
                acc[m][n] = __builtin_amdgcn_mfma_f32_16x16x32_bf16(
                    af[m], bfr[n][0], acc[m][n], 0, 0, 0);
        __builtin_amdgcn_s_setprio(0);

        if (dostage) STAGE(curb ^ 1, kt + 1, 1);
        bf16x8 ag[4];
        #pragma unroll
        for (int m = 0; m < 4; ++m) {
            const int row = wr * 64 + m * 16 + lr;
            ag[m] = *(const bf16x8*)(Abase + row * 128 + (((4 + lk) ^ (row & 7)) << 4));
        }
        asm volatile("s_waitcnt lgkmcnt(0)" ::: "memory");
        __builtin_amdgcn_sched_barrier(0);
        __builtin_amdgcn_s_setprio(1);
        #pragma unroll
        for (int m = 0; m < 4; ++m)
            #pragma unroll
            for (int n = 0; n < 4; ++n)
                acc[m][n] = __builtin_amdgcn_mfma_f32_16x16x32_bf16(
                    ag[m], bfr[n][1], acc[m][n], 0, 0, 0);
        __builtin_amdgcn_s_setprio(0);
        __builtin_amdgcn_s_barrier();
    }

    #pragma unroll
    for (int m = 0; m < 4; ++m) {
        #pragma unroll
        for (int j = 0; j < 4; ++j) {
            const int row = bm + wr * 64 + m * 16 + lk * 4 + j;
            int b_ = 0, t_ = 0;
            if constexpr (EPI == EPI_QKV || EPI == EPI_KV) { b_ = row / p0; t_ = row % p0; }
            #pragma unroll
            for (int n = 0; n < 4; ++n) {
                const int col = bn + wc * 64 + n * 16 + lr;
                if constexpr (EPI == EPI_F32) {
                    float v = acc[m][n][j] + bias[col];
                    __builtin_nontemporal_store(v, &outF[(size_t)row * ldo + col]);
                } else if constexpr (EPI == EPI_ADD) {
                    float v = acc[m][n][j] + bias[col];
                    outF[(size_t)row * ldo + col] += v;
                } else if constexpr (EPI == EPI_GELU) {
                    float v = acc[m][n][j] + bias[col];
                    float u = 1.5957691216057308f * (v + 0.044715f * v * v * v);
                    float g_ = v / (1.0f + __expf(-u));
                    outB[(size_t)row * ldo + col] = (bf16_t)g_;
                } else if constexpr (EPI == EPI_QKV) {
                    float v = acc[m][n][j] + bias[col];
                    int h = col >> 6, d = col & 63;
                    outB[(((size_t)b_ * NH + h) * p0 + t_) * ND + d] = (bf16_t)v;
                } else if constexpr (EPI == EPI_KV) {
                    if (col < NC) {   // K half -> [B][H][NTK][D]
                        float v = acc[m][n][j] + bias[col];
                        int h = col >> 6, d = col & 63;
                        outB[(((size_t)b_ * NH + h) * NTK + t_) * ND + d] = (bf16_t)v;
                    } else {          // V half -> [B][H][D][NTK]
                        int c2_ = col - NC;
                        float v = acc[m][n][j] + bias2[c2_];
                        int h = c2_ >> 6, d = c2_ & 63;
                        outB2[(((size_t)b_ * NH + h) * ND + d) * NTK + t_] = (bf16_t)v;
                    }
                }
            }
        }
    }
}

template<int EPI>
__global__ __launch_bounds__(256) void gemm128(
    const bf16_t* __restrict__ A, const bf16_t* __restrict__ Bt,
    const float* __restrict__ bias, const float* __restrict__ bias2,
    float* __restrict__ outF, bf16_t* __restrict__ outB, bf16_t* __restrict__ outB2,
    int M, int N, int K, int p0, int ldo, int gm)
{
    __shared__ bf16_t sm[32768];
    gemm128_body<EPI>(sm, blockIdx.x, gridDim.x, A, Bt, bias, bias2,
                      outF, outB, outB2, M, N, K, p0, ldo, gm);
}

// Fused Q + KV projection: blocks [0,256) Q-GEMM, [256,832) KV-GEMM.
__global__ __launch_bounds__(256) void qkv_fused(
    const bf16_t* __restrict__ hbuf, const bf16_t* __restrict__ kvbuf,
    const bf16_t* __restrict__ wtq, const bf16_t* __restrict__ wtkv,
    const float* __restrict__ bq, const float* __restrict__ bk,
    const float* __restrict__ bv,
    bf16_t* __restrict__ qbuf, bf16_t* __restrict__ kbuf, bf16_t* __restrict__ vtbuf)
{
    __shared__ bf16_t sm[32768];
    if (blockIdx.x < 256) {
        gemm128_body<EPI_QKV>(sm, blockIdx.x, 256, hbuf, wtq, bq, nullptr,
                              nullptr, qbuf, nullptr, NB * NT, NC, NC, NT, 0, 8);
    } else {
        gemm128_body<EPI_KV>(sm, blockIdx.x - 256, 576, kvbuf, wtkv, bk, bv,
                             nullptr, kbuf, vtbuf, NB * NTK, 2 * NC, NC, NTK, 0, 6);
    }
}

// ---------------------------------------------------------------------------
// Legacy 128x128/BK=32 GEMM (only for tiny m2 GEMM).
// ---------------------------------------------------------------------------
template<int EPI>
__global__ __launch_bounds__(256) void gemm_bt(
    const bf16_t* __restrict__ A, const bf16_t* __restrict__ Bt,
    const float* __restrict__ bias, const float* __restrict__ bias2,
    float* __restrict__ outF, bf16_t* __restrict__ outB, bf16_t* __restrict__ outB2,
    int M, int N, int K, int p0, int ldo, int gm)
{
    __shared__ bf16_t lA[128 * 32];
    __shared__ bf16_t lB[128 * 32];
    const int tid = threadIdx.x;
    const int nwg = gridDim.x;
    const int bid = blockIdx.x;
    const int xcd = bid & 7, base = bid >> 3;
    const int qq = nwg >> 3, rr = nwg & 7;
    int wg = (xcd < rr ? xcd * (qq + 1) : rr * (qq + 1) + (xcd - rr) * qq) + base;
    const int nnt = N >> 7;
    const int gsz = gm * nnt;
    const int g = wg / gsz, r2 = wg - g * gsz;
    const int ntl = r2 / gm, mt = g * gm + (r2 - ntl * gm);
    const int bm = mt * 128, bn = ntl * 128;
    const bf16_t* Ab = A + (size_t)bm * K;
    const bf16_t* Bb = Bt + (size_t)bn * K;
    const int wave = tid >> 6, lane = tid & 63;
    const int wr = wave >> 1, wc = wave & 1;
    const int lr = lane & 15, lk = lane >> 4;
    f32x4 acc[4][4] = {};
    const int nk = K >> 5;
    const int c1 = tid, c2 = tid + 256;
    for (int kt = 0; kt < nk; ++kt) {
        __syncthreads();
        const bf16_t* Abk = Ab + kt * 32;
        const bf16_t* Bbk = Bb + kt * 32;
        GLOAD_LDS16(Abk + (size_t)(c1 >> 2) * K + (c1 & 3) * 8, (char*)lA + c1 * 16);
        GLOAD_LDS16(Abk + (size_t)(c2 >> 2) * K + (c2 & 3) * 8, (char*)lA + c2 * 16);
        GLOAD_LDS16(Bbk + (size_t)(c1 >> 2) * K + (c1 & 3) * 8, (char*)lB + c1 * 16);
        GLOAD_LDS16(Bbk + (size_t)(c2 >> 2) * K + (c2 & 3) * 8, (char*)lB + c2 * 16);
        __syncthreads();
        bf16x8 af[4], bfr[4];
        #pragma unroll
        for (int m = 0; m < 4; ++m)
            af[m] = *(const bf16x8*)&lA[(wr * 64 + m * 16 + lr) * 32 + lk * 8];
        #pragma unroll
        for (int n = 0; n < 4; ++n)
            bfr[n] = *(const bf16x8*)&lB[(wc * 64 + n * 16 + lr) * 32 + lk * 8];
        #pragma unroll
        for (int m = 0; m < 4; ++m)
            #pragma unroll
            for (int n = 0; n < 4; ++n)
                acc[m][n] = __builtin_amdgcn_mfma_f32_16x16x32_bf16(af[m], bfr[n], acc[m][n], 0, 0, 0);
    }
    #pragma unroll
    for (int m = 0; m < 4; ++m) {
        #pragma unroll
        for (int j = 0; j < 4; ++j) {
            const int row = bm + wr * 64 + m * 16 + lk * 4 + j;
            #pragma unroll
            for (int n = 0; n < 4; ++n) {
                const int col = bn + wc * 64 + n * 16 + lr;
                if constexpr (EPI == EPI_F32) {
                    float v = acc[m][n][j] + bias[col];
                    __builtin_nontemporal_store(v, &outF[(size_t)row * ldo + col]);
                }
            }
        }
    }
}

// ---------------------------------------------------------------------------
// Transpose+cast body + wrappers (single + batched per-layer, JIT)
// ---------------------------------------------------------------------------
__device__ __forceinline__ void tc_body(
    const float* __restrict__ W, bf16_t* __restrict__ Wt,
    int K, int N, int k0, int n0, int t)
{
    __shared__ float tile[64][65];
    #pragma unroll
    for (int i = 0; i < 4; ++i) {
        const int idx = t + i * 256;
        const int r = idx >> 4, c4 = (idx & 15) << 2;
        const float4 v = *(const float4*)(W + (size_t)(k0 + r) * N + n0 + c4);
        tile[r][c4 + 0] = v.x; tile[r][c4 + 1] = v.y;
        tile[r][c4 + 2] = v.z; tile[r][c4 + 3] = v.w;
    }
    __syncthreads();
    #pragma unroll
    for (int i = 0; i < 4; ++i) {
        const int idx = t + i * 256;
        const int r = idx >> 4, c4 = (idx & 15) << 2;
        bf16x4 o = {(bf16_t)tile[c4 + 0][r], (bf16_t)tile[c4 + 1][r],
                    (bf16_t)tile[c4 + 2][r], (bf16_t)tile[c4 + 3][r]};
        *(bf16x4*)(Wt + (size_t)(n0 + r) * K + k0 + c4) = o;
    }
}

__global__ __launch_bounds__(256) void transpose_cast(
    const float* __restrict__ W, bf16_t* __restrict__ Wt, int K, int N)
{
    tc_body(W, Wt, K, N, blockIdx.x << 6, blockIdx.y << 6, threadIdx.x);
}

__global__ __launch_bounds__(256) void transpose_layer(
    const float* __restrict__ Wq, const float* __restrict__ Wk,
    const float* __restrict__ Wv, const float* __restrict__ Wo,
    const float* __restrict__ W1, const float* __restrict__ W2,
    bf16_t* __restrict__ wtq, bf16_t* __restrict__ wtkv,
    bf16_t* __restrict__ wto, bf16_t* __restrict__ wt1, bf16_t* __restrict__ wt2)
{
    const int bid = blockIdx.x;
    const float* W; bf16_t* Wt; int K, N, k0, n0;
    if (bid < 1024) {
        const int which = bid >> 8, r = bid & 255;
        K = NC; N = NC;
        k0 = (r & 15) << 6; n0 = (r >> 4) << 6;
        W  = (which == 0) ? Wq : (which == 1) ? Wk : (which == 2) ? Wv : Wo;
        Wt = (which == 0) ? wtq : (which == 1) ? wtkv
           : (which == 2) ? (wtkv + (size_t)NC * NC) : wto;
    } else if (bid < 2048) {
        const int r = bid - 1024;
        K = NC; N = 4 * NC;
        k0 = (r & 15) << 6; n0 = (r >> 4) << 6;
        W = W1; Wt = wt1;
    } else {
        const int r = bid - 2048;
        K = 4 * NC; N = NC;
        k0 = (r & 63) << 6; n0 = (r >> 6) << 6;
        W = W2; Wt = wt2;
    }
    tc_body(W, Wt, K, N, k0, n0, threadIdx.x);
}

// ---------------------------------------------------------------------------
// LayerNorm over C=1024. MODE 0/1/3 as before.
// ---------------------------------------------------------------------------
template<int MODE>
__global__ __launch_bounds__(256) void ln_row(
    const float* __restrict__ X, const float* __restrict__ sw,
    const float* __restrict__ bw, float* __restrict__ outF,
    bf16_t* __restrict__ outB, bf16_t* __restrict__ outB2)
{
    const int row = blockIdx.x;
    const int t = threadIdx.x;
    const float4 v = ((const float4*)(X + (size_t)row * NC))[t];
    float s1 = v.x + v.y + v.z + v.w;
    float s2 = v.x * v.x + v.y * v.y + v.z * v.z + v.w * v.w;
    #pragma unroll
    for (int off = 32; off > 0; off >>= 1) { s1 += __shfl_xor(s1, off); s2 += __shfl_xor(s2, off); }
    __shared__ float rs1[4], rs2[4];
    if ((t & 63) == 0) { rs1[t >> 6] = s1; rs2[t >> 6] = s2; }
    __syncthreads();
    s1 = rs1[0] + rs1[1] + rs1[2] + rs1[3];
    s2 = rs2[0] + rs2[1] + rs2[2] + rs2[3];
    const float mu = s1 * (1.0f / NC);
    const float var = s2 * (1.0f / NC) - mu * mu;
    const float rstd = rsqrtf(var + 1e-6f);
    const int c = t * 4;
    const float4 sv = ((const float4*)sw)[t];
    const float4 bv = ((const float4*)bw)[t];
    float y0 = (v.x - mu) * rstd * sv.x + bv.x;
    float y1 = (v.y - mu) * rstd * sv.y + bv.y;
    float y2 = (v.z - mu) * rstd * sv.z + bv.z;
    float y3 = (v.w - mu) * rstd * sv.w + bv.w;
    size_t dst;
    if constexpr (MODE == 1) dst = ((size_t)(row / NO) * NTK + (row % NO)) * NC + c;
    else dst = (size_t)row * NC + c;
    bf16x4 o = {(bf16_t)y0, (bf16_t)y1, (bf16_t)y2, (bf16_t)y3};
    *(bf16x4*)(outB + dst) = o;
    if constexpr (MODE == 3) {
        const int b_ = row >> 10, t_ = row & 1023;
        bf16x4 o2 = {(bf16_t)v.x, (bf16_t)v.y, (bf16_t)v.z, (bf16_t)v.w};
        *(bf16x4*)(outB2 + ((size_t)b_ * NTK + NO + t_) * NC + c) = o2;
    }
}

// ---------------------------------------------------------------------------
// Final LN fused with mask-cast + new_mem extraction.
// ---------------------------------------------------------------------------
__global__ __launch_bounds__(256) void ln_final(
    const float* __restrict__ X, const float* __restrict__ sw,
    const float* __restrict__ bw, const int* __restrict__ tokens,
    bf16_t* __restrict__ xm, float* __restrict__ outMem)
{
    const int row = blockIdx.x;
    const int t = threadIdx.x;
    const float4 v = ((const float4*)(X + (size_t)row * NC))[t];
    float s1 = v.x + v.y + v.z + v.w;
    float s2 = v.x * v.x + v.y * v.y + v.z * v.z + v.w * v.w;
    #pragma unroll
    for (int off = 32; off > 0; off >>= 1) { s1 += __shfl_xor(s1, off); s2 += __shfl_xor(s2, off); }
    __shared__ float rs1[4], rs2[4];
    if ((t & 63) == 0) { rs1[t >> 6] = s1; rs2[t >> 6] = s2; }
    __syncthreads();
    s1 = rs1[0] + rs1[1] + rs1[2] + rs1[3];
    s2 = rs2[0] + rs2[1] + rs2[2] + rs2[3];
    const float mu = s1 * (1.0f / NC);
    const float var = s2 * (1.0f / NC) - mu * mu;
    const float rstd = rsqrtf(var + 1e-6f);
    const int c = t * 4;
    const float4 sv = ((const float4*)sw)[t];
    const float4 bv = ((const float4*)bw)[t];
    float y0 = (v.x - mu) * rstd * sv.x + bv.x;
    float y1 = (v.y - mu) * rstd * sv.y + bv.y;
    float y2 = (v.z - mu) * rstd * sv.z + bv.z;
    float y3 = (v.w - mu) * rstd * sv.w + bv.w;
    const bool ok = tokens[row] != 0;
    bf16x4 o;
    if (ok) { o = (bf16x4){(bf16_t)y0, (bf16_t)y1, (bf16_t)y2, (bf16_t)y3}; }
    else    { o = (bf16x4){(bf16_t)0.f, (bf16_t)0.f, (bf16_t)0.f, (bf16_t)0.f}; }
    *(bf16x4*)(xm + (size_t)row * NC + c) = o;
    const int b_ = row >> 10, t_ = row & 1023;
    if (t_ >= NT - NO) {
        float4 f; f.x = y0; f.y = y1; f.z = y2; f.w = y3;
        *(float4*)(outMem + ((size_t)b_ * NO + (t_ - (NT - NO))) * NC + c) = f;
    }
}

// ---------------------------------------------------------------------------
// Flash attention: 32 q-rows per wave (2 subtiles sharing K/V fragment
// loads), 4 waves/block, no barriers, 64-key tiles, LPT y-order.
// ---------------------------------------------------------------------------
__global__ __launch_bounds__(256) void attn_kernel(
    const bf16_t* __restrict__ Q, const bf16_t* __restrict__ Kb,
    const bf16_t* __restrict__ Vt, const int* __restrict__ tokens,
    bf16_t* __restrict__ Ob)
{
    const int bh = blockIdx.x;
    const int b = bh >> 4, h = bh & 15;
    const int w = threadIdx.x >> 6;
    const int lane = threadIdx.x & 63;
    const int yt = gridDim.y - 1 - blockIdx.y;   // LPT: long tiles first
    const int q0 = (yt << 7) + (w << 5);
    const int lr = lane & 15, lk = lane >> 4;
    const bf16_t* Qp = Q + ((size_t)bh * NT + q0) * ND;
    bf16x8 qf[2][2];
    #pragma unroll
    for (int qs = 0; qs < 2; ++qs) {
        qf[qs][0] = *(const bf16x8*)(Qp + (qs * 16 + lr) * ND + lk * 8);
        qf[qs][1] = *(const bf16x8*)(Qp + (qs * 16 + lr) * ND + 32 + lk * 8);
    }
    const bf16_t* Kbase = Kb + (size_t)bh * NTK * ND;
    const bf16_t* Vbase = Vt + (size_t)bh * ND * NTK;
    const int* tokb = tokens + b * NT;
    float mrow[2][4] = {{-1e30f, -1e30f, -1e30f, -1e30f}, {-1e30f, -1e30f, -1e30f, -1e30f}};
    float lsum[2][4] = {};
    f32x4 acc[2][4] = {};
    __shared__ bf16_t pb[4][2][16 * 64];
    const int kmax = NO + q0 + 32;
    for (int k0 = 0; k0 < kmax; k0 += 64) {
        f32x4 st[2][4] = {};
        __builtin_amdgcn_s_setprio(1);
        #pragma unroll
        for (int nt = 0; nt < 4; ++nt) {
            const bf16_t* Kp = Kbase + (size_t)(k0 + nt * 16 + lr) * ND + lk * 8;
            bf16x8 kf0 = *(const bf16x8*)(Kp);
            bf16x8 kf1 = *(const bf16x8*)(Kp + 32);
            #pragma unroll
            for (int qs = 0; qs < 2; ++qs) {
                st[qs][nt] = __builtin_amdgcn_mfma_f32_16x16x32_bf16(qf[qs][0], kf0, st[qs][nt], 0, 0, 0);
                st[qs][nt] = __builtin_amdgcn_mfma_f32_16x16x32_bf16(qf[qs][1], kf1, st[qs][nt], 0, 0, 0);
            }
        }
        __builtin_amdgcn_s_setprio(0);
        #pragma unroll
        for (int qs = 0; qs < 2; ++qs) {
            char* pbq = (char*)pb[w][qs];
            float sc[4][4];
            float tmax[4] = {-1e30f, -1e30f, -1e30f, -1e30f};
            #pragma unroll
            for (int nt = 0; nt < 4; ++nt) {
                const int key = k0 + nt * 16 + lr;
                const int kt = key - NO;
                const int kts = kt < 0 ? 0 : kt;
                const bool keyok = (kt < 0) | (tokb[kts] != 0);
                #pragma unroll
                for (int j = 0; j < 4; ++j) {
                    const int qrow = q0 + qs * 16 + lk * 4 + j;
                    const bool ok = keyok && (kt <= qrow);
                    const float s = ok ? st[qs][nt][j] * 0.125f : -1e9f;
                    sc[nt][j] = s;
                    tmax[j] = fmaxf(tmax[j], s);
                }
            }
            #pragma unroll
            for (int off = 1; off < 16; off <<= 1)
                #pragma unroll
                for (int j = 0; j < 4; ++j) tmax[j] = fmaxf(tmax[j], __shfl_xor(tmax[j], off));
            float resc[4], p[4][4], psum[4] = {0.f, 0.f, 0.f, 0.f};
            #pragma unroll
            for (int j = 0; j < 4; ++j) {
                const float mnew = fmaxf(mrow[qs][j], tmax[j]);
                resc[j] = __expf(mrow[qs][j] - mnew);
                mrow[qs][j] = mnew;
            }
            #pragma unroll
            for (int nt = 0; nt < 4; ++nt)
                #pragma unroll
                for (int j = 0; j < 4; ++j) { p[nt][j] = __expf(sc[nt][j] - mrow[qs][j]); psum[j] += p[nt][j]; }
            #pragma unroll
            for (int off = 1; off < 16; off <<= 1)
                #pragma unroll
                for (int j = 0; j < 4; ++j) psum[j] += __shfl_xor(psum[j], off);
            #pragma unroll
            for (int j = 0; j < 4; ++j) lsum[qs][j] = lsum[qs][j] * resc[j] + psum[j];
            #pragma unroll
            for (int dt = 0; dt < 4; ++dt)
                #pragma unroll
                for (int j = 0; j < 4; ++j) acc[qs][dt][j] *= resc[j];
            #pragma unroll
            for (int nt = 0; nt < 4; ++nt)
                #pragma unroll
                for (int j = 0; j < 4; ++j) {
                    const int row = lk * 4 + j;
                    const int byt = (row << 7) + ((((nt << 4) + lr) << 1) ^ ((row & 7) << 4));
                    *(bf16_t*)(pbq + byt) = (bf16_t)p[nt][j];
                }
        }
        const int swz = (lr & 7) << 4;
        bf16x8 pa[2][2];
        #pragma unroll
        for (int qs = 0; qs < 2; ++qs) {
            const char* pbq = (const char*)pb[w][qs];
            pa[qs][0] = *(const bf16x8*)(pbq + ((lr << 7) + (((lk << 4)) ^ swz)));
            pa[qs][1] = *(const bf16x8*)(pbq + ((lr << 7) + ((64 + (lk << 4)) ^ swz)));
        }
        __builtin_amdgcn_s_setprio(1);
        #pragma unroll
        for (int dt = 0; dt < 4; ++dt) {
            const bf16_t* Vp = Vbase + (size_t)(dt * 16 + lr) * NTK + k0 + lk * 8;
            bf16x8 vf0 = *(const bf16x8*)(Vp);
            bf16x8 vf1 = *(const bf16x8*)(Vp + 32);
            #pragma unroll
            for (int qs = 0; qs < 2; ++qs) {
                acc[qs][dt] = __builtin_amdgcn_mfma_f32_16x16x32_bf16(pa[qs][0], vf0, acc[qs][dt], 0, 0, 0);
                acc[qs][dt] = __builtin_amdgcn_mfma_f32_16x16x32_bf16(pa[qs][1], vf1, acc[qs][dt], 0, 0, 0);
            }
        }
        __builtin_amdgcn_s_setprio(0);
    }
    #pragma unroll
    for (int qs = 0; qs < 2; ++qs)
        #pragma unroll
        for (int dt = 0; dt < 4; ++dt)
            #pragma unroll
            for (int j = 0; j < 4; ++j)
                Ob[((size_t)b * NT + q0 + qs * 16 + lk * 4 + j) * NC + h * ND + dt * 16 + lr] =
                    (bf16_t)(acc[qs][dt][j] / lsum[qs][j]);
}

// ---------------------------------------------------------------------------
// Small kernels
// ---------------------------------------------------------------------------
__global__ __launch_bounds__(256) void sum_proj_kernel(
    const float* __restrict__ ssum, const float* __restrict__ sumw,
    const float* __restrict__ alpha, float* __restrict__ add)
{
    const int b = blockIdx.y;
    const int c = blockIdx.x * 256 + threadIdx.x;
    float a = 0.f;
    for (int k = 0; k < NC; ++k) a += ssum[b * NC + k] * sumw[(size_t)k * NC + c];
    add[b * NC + c] = a * sigmoidf_(alpha[c]);
}

__global__ __launch_bounds__(256) void embed_kernel(
    const int* __restrict__ tokens, const int* __restrict__ posoff,
    const float* __restrict__ tokw, const float* __restrict__ posw,
    const float* __restrict__ add, float* __restrict__ X)
{
    const int bt = blockIdx.x;
    const int b = bt >> 10, t = bt & 1023;
    const int c = threadIdx.x * 4;
    const int tok = tokens[bt];
    int p = t + posoff[0];
    p = p < 0 ? 0 : (p > NS - 1 ? NS - 1 : p);
    const float4 tv = *(const float4*)(tokw + (size_t)tok * NC + c);
    const float4 pv = *(const float4*)(posw + (size_t)p * NC + c);
    const float4 av = *(const float4*)(add + b * NC + c);
    float4 o;
    o.x = tv.x + pv.x + av.x; o.y = tv.y + pv.y + av.y;
    o.z = tv.z + pv.z + av.z; o.w = tv.w + pv.w + av.w;
    *(float4*)(X + (size_t)bt * NC + c) = o;
}

__global__ __launch_bounds__(256) void cast_f32_bf16_kernel(
    const float* __restrict__ in, bf16_t* __restrict__ out)
{
    const size_t i = ((size_t)blockIdx.x * 256 + threadIdx.x) * 4;
    const float4 v = *(const float4*)(in + i);
    bf16x4 o = {(bf16_t)v.x, (bf16_t)v.y, (bf16_t)v.z, (bf16_t)v.w};
    *(bf16x4*)(out + i) = o;
}

__global__ __launch_bounds__(256) void sumpart_kernel(
    const bf16_t* __restrict__ XM, float* __restrict__ sbuf)
{
    const int b = blockIdx.z;
    const int c = blockIdx.x * 256 + threadIdx.x;
    const int t0 = blockIdx.y * 64;
    float a = 0.f;
    for (int t = t0; t < t0 + 64; ++t)
        a += (float)XM[((size_t)b * NT + t) * NC + c];
    atomicAdd(&sbuf[b * NC + c], a);
}

__global__ __launch_bounds__(256) void ssum_out_kernel(
    const float* __restrict__ sbuf, const int* __restrict__ tokens,
    const float* __restrict__ ssum, const float* __restrict__ lamp, float* __restrict__ out)
{
    const int b = blockIdx.y;
    const int c = blockIdx.x * 256 + threadIdx.x;
    int cnt = 0;
    for (int t = 0; t < NT; ++t) cnt += (tokens[b * NT + t] != 0);
    const float summary = sbuf[b * NC + c] / ((float)cnt + 1e-6f);
    const float lam = sigmoidf_(lamp[c]);
    out[b * NC + c] = ssum[b * NC + c] * lam + summary * (1.0f - lam);
}

// ---------------------------------------------------------------------------
extern "C" void kernel_launch(void* const* d_in, const int* in_sizes, int n_in,
                              void* d_out, int out_size, void* d_ws, size_t ws_size,
                              hipStream_t stream)
{
    (void)in_sizes; (void)n_in; (void)out_size; (void)ws_size;
    const int*   tokens   = (const int*)d_in[0];
    const int*   posoff   = (const int*)d_in[1];
    const float* mem      = (const float*)d_in[2];
    const float* ssum     = (const float*)d_in[3];
    const float* tok_emb  = (const float*)d_in[4];
    const float* pos_emb  = (const float*)d_in[5];
    const float* mem_w    = (const float*)d_in[6];
    const float* mem_b    = (const float*)d_in[7];
    const float* memln_s  = (const float*)d_in[8];
    const float* memln_b  = (const float*)d_in[9];
    const float* alpha_p  = (const float*)d_in[10];
    const float* sum_w    = (const float*)d_in[11];
    const float* ln1_s    = (const float*)d_in[12];
    const float* ln1_b    = (const float*)d_in[13];
    const float* Wq       = (const float*)d_in[14];
    const float* bq       = (const float*)d_in[15];
    const float* Wk       = (const float*)d_in[16];
    const float* bk       = (const float*)d_in[17];
    const float* Wv       = (const float*)d_in[18];
    const float* bv       = (const float*)d_in[19];
    const float* Wo       = (const float*)d_in[20];
    const float* bo       = (const float*)d_in[21];
    const float* ln2_s    = (const float*)d_in[22];
    const float* ln2_b    = (const float*)d_in[23];
    const float* W1       = (const float*)d_in[24];
    const float* b1       = (const float*)d_in[25];
    const float* W2       = (const float*)d_in[26];
    const float* b2       = (const float*)d_in[27];
    const float* fln_s    = (const float*)d_in[28];
    const float* fln_b    = (const float*)d_in[29];
    const float* head_w   = (const float*)d_in[30];
    const float* head_b   = (const float*)d_in[31];
    const float* lam_p    = (const float*)d_in[32];

    float* out_mem    = (float*)d_out;                          // B*O*C
    float* out_ssum   = out_mem + (size_t)NB * NO * NC;         // B*C
    float* out_logits = out_ssum + (size_t)NB * NC;             // B*T*V

    char* wp = (char*)d_ws;
    auto alloc = [&](size_t bytes) { char* p = wp; wp += (bytes + 255) & ~(size_t)255; return p; };
    bf16_t* wt_head = (bf16_t*)alloc((size_t)NV * NC * 2);
    bf16_t* wt_mem  = (bf16_t*)alloc((size_t)NC * NC * 2);
    bf16_t* wt_q    = (bf16_t*)alloc((size_t)NC * NC * 2);
    bf16_t* wt_kv   = (bf16_t*)alloc((size_t)2 * NC * NC * 2);
    bf16_t* wt_o    = (bf16_t*)alloc((size_t)NC * NC * 2);
    bf16_t* wt_1    = (bf16_t*)alloc((size_t)NC * 4 * NC * 2);
    bf16_t* wt_2    = (bf16_t*)alloc((size_t)NC * 4 * NC * 2);
    float*  xbuf    = (float*)alloc((size_t)NB * NT * NC * 4);
    bf16_t* hbuf    = (bf16_t*)alloc((size_t)NB * NT * NC * 2);
    bf16_t* kvbuf   = (bf16_t*)alloc((size_t)NB * NTK * NC * 2);
    bf16_t* qbuf    = (bf16_t*)alloc((size_t)NB * NT * NC * 2);
    bf16_t* kbuf    = (bf16_t*)alloc((size_t)NB * NTK * NC * 2);
    bf16_t* vtbuf   = (bf16_t*)alloc((size_t)NB * NTK * NC * 2);
    bf16_t* obuf    = (bf16_t*)alloc((size_t)NB * NT * NC * 2);
    bf16_t* midbuf  = (bf16_t*)alloc((size_t)NB * NT * 4 * NC * 2);
    bf16_t* xmbuf   = (bf16_t*)alloc((size_t)NB * NT * NC * 2);
    bf16_t* membf   = (bf16_t*)alloc((size_t)NB * NO * NC * 2);
    float*  m2f     = (float*)alloc((size_t)NB * NO * NC * 4);
    float*  addb    = (float*)alloc((size_t)NB * NC * 4);
    float*  sbuf    = (float*)alloc((size_t)NB * NC * 4);

    hipMemsetAsync(sbuf, 0, (size_t)NB * NC * 4, stream);

    // weight transposes (head + mem) — head stays upfront (consumed last but
    // it's one big stream; mem consumed immediately)
    transpose_cast<<<dim3(NC / 64, NV / 64), 256, 0, stream>>>(head_w, wt_head, NC, NV);
    transpose_cast<<<dim3(NC / 64, NC / 64), 256, 0, stream>>>(mem_w, wt_mem, NC, NC);

    // m2 = LN(mem @ mem_w + mem_b) -> kv rows [0,O)
    cast_f32_bf16_kernel<<<(NB * NO * NC) / 1024, 256, 0, stream>>>(mem, membf);
    gemm_bt<EPI_F32><<<32, 256, 0, stream>>>(
        membf, wt_mem, mem_b, nullptr, m2f, nullptr, nullptr, NB * NO, NC, NC, 0, NC, 4);
    ln_row<1><<<NB * NO, 256, 0, stream>>>(m2f, memln_s, memln_b, nullptr, kvbuf, nullptr);

    // x = tok_emb[tokens] + pos_emb + (ssum @ sum_w)*sigmoid(alpha)
    sum_proj_kernel<<<dim3(NC / 256, NB), 256, 0, stream>>>(ssum, sum_w, alpha_p, addb);
    embed_kernel<<<NB * NT, 256, 0, stream>>>(tokens, posoff, tok_emb, pos_emb, addb, xbuf);

    for (int i = 0; i < NL; ++i) {
        // JIT per-layer transposes (keeps weights L3-warm for the GEMMs)
        transpose_layer<<<3072, 256, 0, stream>>>(
            Wq + (size_t)i * NC * NC, Wk + (size_t)i * NC * NC,
            Wv + (size_t)i * NC * NC, Wo + (size_t)i * NC * NC,
            W1 + (size_t)i * NC * 4 * NC, W2 + (size_t)i * 4 * NC * NC,
            wt_q, wt_kv, wt_o, wt_1, wt_2);

        // ln1 + x->kv cast fused
        ln_row<3><<<NB * NT, 256, 0, stream>>>(xbuf, ln1_s + i * NC, ln1_b + i * NC, nullptr, hbuf, kvbuf);

        // Q + KV projections fused into ONE launch (832 blocks)
        qkv_fused<<<832, 256, 0, stream>>>(
            hbuf, kvbuf, wt_q, wt_kv, bq + i * NC, bk + i * NC, bv + i * NC,
            qbuf, kbuf, vtbuf);

        attn_kernel<<<dim3(NB * NH, NT / 128), 256, 0, stream>>>(qbuf, kbuf, vtbuf, tokens, obuf);

        gemm128<EPI_ADD><<<256, 256, 0, stream>>>(
            obuf, wt_o, bo + i * NC, nullptr, xbuf, nullptr, nullptr, NB * NT, NC, NC, 0, NC, 8);

        ln_row<0><<<NB * NT, 256, 0, stream>>>(xbuf, ln2_s + i * NC, ln2_b + i * NC, nullptr, hbuf, nullptr);
        // FFN1: 256^2 engine (GELU epilogue)
        gemm8p<1><<<256, 512, 0, stream>>>(
            hbuf, wt_1, b1 + (size_t)i * 4 * NC, nullptr, midbuf, NB * NT, 4 * NC, NC, 4 * NC, 4);
        // FFN2: round-10 proven config (EPI_ADD, ks=1)
        gemm128<EPI_ADD><<<256, 256, 0, stream>>>(
            midbuf, wt_2, b2 + i * NC, nullptr, xbuf, nullptr, nullptr, NB * NT, NC, 4 * NC, 0, NC, 8);
    }

    // final LN fused with mask-cast + new_mem extraction
    ln_final<<<NB * NT, 256, 0, stream>>>(xbuf, fln_s, fln_b, tokens, xmbuf, out_mem);
    sumpart_kernel<<<dim3(NC / 256, NT / 64, NB), 256, 0, stream>>>(xmbuf, sbuf);
    ssum_out_kernel<<<dim3(NC / 256, NB), 256, 0, stream>>>(sbuf, tokens, ssum, lam_p, out_ssum);
    // head: 256^2 engine
    gemm8p<0><<<2000, 512, 0, stream>>>(
        xmbuf, wt_head, head_b, out_logits, nullptr, NB * NT, NV, NC, NV, 4);
}

// Round 16
// 1657.392 us; speedup vs baseline: 1.1009x; 1.0075x over previous
//
#include <hip/hip_runtime.h>
#include <hip/hip_bf16.h>

typedef __bf16 bf16_t;
typedef __bf16 bf16x8 __attribute__((ext_vector_type(8)));
typedef __bf16 bf16x4 __attribute__((ext_vector_type(4)));
typedef float f32x4 __attribute__((ext_vector_type(4)));

#define NB 4
#define NT 1024
#define NO 128
#define NC 1024
#define NH 16
#define NL 4
#define NV 32000
#define NS 4096
#define ND 64
#define NTK (NO + NT)   // 1152

#define GLOAD_LDS16(g, l) __builtin_amdgcn_global_load_lds( \
    (__attribute__((address_space(1))) void*)(g), \
    (__attribute__((address_space(3))) void*)(l), 16, 0, 0)

#define EXP2F(x) __builtin_amdgcn_exp2f(x)

__device__ __forceinline__ float sigmoidf_(float x) { return 1.0f / (1.0f + __expf(-x)); }

#define EPI_F32  0
#define EPI_ADD  1
#define EPI_GELU 2
#define EPI_QKV  3
#define EPI_KV   4

// ---------------------------------------------------------------------------
// 8-wave 256x256 GEMM (round-6 engine): BK=64, 512 thr, double-buffered
// 128KB LDS, counted vmcnt, raw s_barrier, XOR swizzle, fragment reuse.
// EPI 0: f32 nontemporal; 1: GELU->bf16.
// ---------------------------------------------------------------------------
template<int EPI>
__global__ __launch_bounds__(512) void gemm8p(
    const bf16_t* __restrict__ A, const bf16_t* __restrict__ Bt,
    const float* __restrict__ bias, float* __restrict__ outF,
    bf16_t* __restrict__ outB, int M, int N, int K, int ldo, int gm)
{
    __shared__ bf16_t sm[65536];
    const int tid = threadIdx.x;
    const int w = tid >> 6, lane = tid & 63;
    const int wr = w >> 2, wc = w & 3;
    const int lr = lane & 15, lk = lane >> 4;
    const int nwg = gridDim.x;
    const int bid = blockIdx.x;
    const int xcd = bid & 7, base = bid >> 3;
    const int qq = nwg >> 3, rr = nwg & 7;
    int wg = (xcd < rr ? xcd * (qq + 1) : rr * (qq + 1) + (xcd - rr) * qq) + base;
    const int nnt = N >> 8;
    const int gsz = gm * nnt;
    const int g = wg / gsz, r2 = wg - g * gsz;
    const int ntl = r2 / gm, mt = g * gm + (r2 - ntl * gm);
    const int bm = mt << 8, bn = ntl << 8;
    const bf16_t* Ab = A + (size_t)bm * K;
    const bf16_t* Bb = Bt + (size_t)bn * K;
    const int srow = tid >> 3;
    const int scol = ((tid & 7) ^ (srow & 7)) << 3;
    const int nk = K >> 6;
    f32x4 acc[8][4] = {};

    auto STAGE = [&](int b, int kt, int h) {
        const bf16_t* gsrc = (h < 2) ? Ab : Bb;
        const int half = h & 1;
        char* lbase = (char*)(sm + ((h < 2) ? 0 : 32768) + b * 16384 + half * 8192);
        #pragma unroll
        for (int i = 0; i < 2; ++i) {
            GLOAD_LDS16(gsrc + (size_t)(half * 128 + i * 64 + srow) * K + kt * 64 + scol,
                        lbase + (i * 512 + tid) * 16);
        }
    };

    #pragma unroll
    for (int h = 0; h < 4; ++h) STAGE(0, 0, h);
    asm volatile("s_waitcnt vmcnt(0)" ::: "memory");
    __builtin_amdgcn_s_barrier();

    for (int kt = 0; kt < nk; ++kt) {
        const int curb = kt & 1;
        const bool dostage = (kt + 1) < nk;
        const char* Abase = (const char*)(sm + curb * 16384);
        const char* Bbase = (const char*)(sm + 32768 + curb * 16384);

        if (dostage) {
            STAGE(curb ^ 1, kt + 1, 0);
            STAGE(curb ^ 1, kt + 1, 1);
            asm volatile("s_waitcnt vmcnt(4)" ::: "memory");
        } else {
            asm volatile("s_waitcnt vmcnt(0)" ::: "memory");
        }
        __builtin_amdgcn_s_barrier();

        bf16x8 bfr[4][2];
        #pragma unroll
        for (int n = 0; n < 4; ++n)
            #pragma unroll
            for (int ks = 0; ks < 2; ++ks) {
                const int row = wc * 64 + n * 16 + lr;
                bfr[n][ks] = *(const bf16x8*)(Bbase + row * 128 + ((((ks << 2) + lk) ^ (row & 7)) << 4));
            }
        bf16x8 af[4][2];
        #pragma unroll
        for (int m = 0; m < 4; ++m)
            #pragma unroll
            for (int ks = 0; ks < 2; ++ks) {
                const int row = wr * 128 + m * 16 + lr;
                af[m][ks] = *(const bf16x8*)(Abase + row * 128 + ((((ks << 2) + lk) ^ (row & 7)) << 4));
            }
        asm volatile("s_waitcnt lgkmcnt(0)" ::: "memory");
        __builtin_amdgcn_sched_barrier(0);
        __builtin_amdgcn_s_setprio(1);
        #pragma unroll
        for (int m = 0; m < 4; ++m)
            #pragma unroll
            for (int n = 0; n < 4; ++n)
                #pragma unroll
                for (int ks = 0; ks < 2; ++ks)
                    acc[m][n] = __builtin_amdgcn_mfma_f32_16x16x32_bf16(
                        af[m][ks], bfr[n][ks], acc[m][n], 0, 0, 0);
        __builtin_amdgcn_s_setprio(0);

        if (dostage) {
            STAGE(curb ^ 1, kt + 1, 2);
            STAGE(curb ^ 1, kt + 1, 3);
        }
        bf16x8 ag[4][2];
        #pragma unroll
        for (int m = 0; m < 4; ++m)
            #pragma unroll
            for (int ks = 0; ks < 2; ++ks) {
                const int row = wr * 128 + 64 + m * 16 + lr;
                ag[m][ks] = *(const bf16x8*)(Abase + row * 128 + ((((ks << 2) + lk) ^ (row & 7)) << 4));
            }
        asm volatile("s_waitcnt lgkmcnt(0)" ::: "memory");
        __builtin_amdgcn_sched_barrier(0);
        __builtin_amdgcn_s_setprio(1);
        #pragma unroll
        for (int m = 0; m < 4; ++m)
            #pragma unroll
            for (int n = 0; n < 4; ++n)
                #pragma unroll
                for (int ks = 0; ks < 2; ++ks)
                    acc[4 + m][n] = __builtin_amdgcn_mfma_f32_16x16x32_bf16(
                        ag[m][ks], bfr[n][ks], acc[4 + m][n], 0, 0, 0);
        __builtin_amdgcn_s_setprio(0);
        __builtin_amdgcn_s_barrier();
    }

    float bv4[4];
    #pragma unroll
    for (int n = 0; n < 4; ++n) bv4[n] = bias[bn + wc * 64 + n * 16 + lr];
    #pragma unroll
    for (int m = 0; m < 8; ++m) {
        #pragma unroll
        for (int j = 0; j < 4; ++j) {
            const int row = bm + wr * 128 + m * 16 + lk * 4 + j;
            #pragma unroll
            for (int n = 0; n < 4; ++n) {
                const int col = bn + wc * 64 + n * 16 + lr;
                float v = acc[m][n][j] + bv4[n];
                if constexpr (EPI == 0) {
                    __builtin_nontemporal_store(v, &outF[(size_t)row * ldo + col]);
                } else {
                    float u = 1.5957691216057308f * (v + 0.044715f * v * v * v);
                    float g_ = v / (1.0f + __expf(-u));
                    outB[(size_t)row * ldo + col] = (bf16_t)g_;
                }
            }
        }
    }
}

// ---------------------------------------------------------------------------
// 4-wave 128x128 GEMM body (round-6 schedule): BK=64, 256 thr, 64 KB LDS,
// counted vmcnt(4), XOR swizzle, B-frags held across both ks-phases.
// ---------------------------------------------------------------------------
template<int EPI>
__device__ __forceinline__ void gemm128_body(
    bf16_t* sm, int bid, int nwg,
    const bf16_t* __restrict__ A, const bf16_t* __restrict__ Bt,
    const float* __restrict__ bias, const float* __restrict__ bias2,
    float* __restrict__ outF, bf16_t* __restrict__ outB, bf16_t* __restrict__ outB2,
    int M, int N, int K, int p0, int ldo, int gm)
{
    char* smb = (char*)sm;
    const int tid = threadIdx.x;
    const int w = tid >> 6, lane = tid & 63;
    const int wr = w >> 1, wc = w & 1;
    const int lr = lane & 15, lk = lane >> 4;
    const int xcd = bid & 7, base = bid >> 3;
    const int qq = nwg >> 3, rr = nwg & 7;
    int wg = (xcd < rr ? xcd * (qq + 1) : rr * (qq + 1) + (xcd - rr) * qq) + base;
    const int nnt = N >> 7;
    const int gsz = gm * nnt;
    const int g = wg / gsz, r2 = wg - g * gsz;
    const int ntl = r2 / gm, mt = g * gm + (r2 - ntl * gm);
    const int bm = mt << 7, bn = ntl << 7;
    const bf16_t* Ab = A + (size_t)bm * K;
    const bf16_t* Bb = Bt + (size_t)bn * K;
    const int srow = tid >> 3;
    const int scol = ((tid & 7) ^ (srow & 7)) << 3;
    const int nk = K >> 6;
    f32x4 acc[4][4] = {};

    auto STAGE = [&](int b, int kt, int h) {
        const bf16_t* gsrc = h ? Bb : Ab;
        char* lbase = smb + h * 32768 + b * 16384;
        #pragma unroll
        for (int i = 0; i < 4; ++i) {
            GLOAD_LDS16(gsrc + (size_t)(i * 32 + srow) * K + kt * 64 + scol,
                        lbase + (i * 256 + tid) * 16);
        }
    };

    STAGE(0, 0, 0); STAGE(0, 0, 1);
    asm volatile("s_waitcnt vmcnt(0)" ::: "memory");
    __builtin_amdgcn_s_barrier();

    for (int kt = 0; kt < nk; ++kt) {
        const int curb = kt & 1;
        const bool dostage = (kt + 1) < nk;
        const char* Abase = smb + curb * 16384;
        const char* Bbase = smb + 32768 + curb * 16384;

        if (dostage) {
            STAGE(curb ^ 1, kt + 1, 0);
            asm volatile("s_waitcnt vmcnt(4)" ::: "memory");
        } else {
            asm volatile("s_waitcnt vmcnt(0)" ::: "memory");
        }
        __builtin_amdgcn_s_barrier();

        bf16x8 bfr[4][2];
        #pragma unroll
        for (int n = 0; n < 4; ++n)
            #pragma unroll
            for (int ks_ = 0; ks_ < 2; ++ks_) {
                const int row = wc * 64 + n * 16 + lr;
                bfr[n][ks_] = *(const bf16x8*)(Bbase + row * 128 + ((((ks_ << 2) + lk) ^ (row & 7)) << 4));
            }
        bf16x8 af[4];
        #pragma unroll
        for (int m = 0; m < 4; ++m) {
            const int row = wr * 64 + m * 16 + lr;
            af[m] = *(const bf16x8*)(Abase + row * 128 + (((lk) ^ (row & 7)) << 4));
        }
        asm volatile("s_waitcnt lgkmcnt(0)" ::: "memory");
        __builtin_amdgcn_sched_barrier(0);
        __builtin_amdgcn_s_setprio(1);
        #pragma unroll
        for (int m = 0; m < 4; ++m)
            #pragma unroll
            for (int n = 0; n < 4; ++n)
                acc[m][n] = __builtin_amdgcn_mfma_f32_16x16x32_bf16(
                    af[m], bfr[n][0], acc[m][n], 0, 0, 0);
        __builtin_amdgcn_s_setprio(0);

        if (dostage) STAGE(curb ^ 1, kt + 1, 1);
        bf16x8 ag[4];
        #pragma unroll
        for (int m = 0; m < 4; ++m) {
            const int row = wr * 64 + m * 16 + lr;
            ag[m] = *(const bf16x8*)(Abase + row * 128 + (((4 + lk) ^ (row & 7)) << 4));
        }
        asm volatile("s_waitcnt lgkmcnt(0)" ::: "memory");
        __builtin_amdgcn_sched_barrier(0);
        __builtin_amdgcn_s_setprio(1);
        #pragma unroll
        for (int m = 0; m < 4; ++m)
            #pragma unroll
            for (int n = 0; n < 4; ++n)
                acc[m][n] = __builtin_amdgcn_mfma_f32_16x16x32_bf16(
                    ag[m], bfr[n][1], acc[m][n], 0, 0, 0);
        __builtin_amdgcn_s_setprio(0);
        __builtin_amdgcn_s_barrier();
    }

    #pragma unroll
    for (int m = 0; m < 4; ++m) {
        #pragma unroll
        for (int j = 0; j < 4; ++j) {
            const int row = bm + wr * 64 + m * 16 + lk * 4 + j;
            int b_ = 0, t_ = 0;
            if constexpr (EPI == EPI_QKV || EPI == EPI_KV) { b_ = row / p0; t_ = row % p0; }
            #pragma unroll
            for (int n = 0; n < 4; ++n) {
                const int col = bn + wc * 64 + n * 16 + lr;
                if constexpr (EPI == EPI_F32) {
                    float v = acc[m][n][j] + bias[col];
                    __builtin_nontemporal_store(v, &outF[(size_t)row * ldo + col]);
                } else if constexpr (EPI == EPI_ADD) {
                    float v = acc[m][n][j] + bias[col];
                    outF[(size_t)row * ldo + col] += v;
                } else if constexpr (EPI == EPI_GELU) {
                    float v = acc[m][n][j] + bias[col];
                    float u = 1.5957691216057308f * (v + 0.044715f * v * v * v);
                    float g_ = v / (1.0f + __expf(-u));
                    outB[(size_t)row * ldo + col] = (bf16_t)g_;
                } else if constexpr (EPI == EPI_QKV) {
                    float v = acc[m][n][j] + bias[col];
                    int h = col >> 6, d = col & 63;
                    outB[(((size_t)b_ * NH + h) * p0 + t_) * ND + d] = (bf16_t)v;
                } else if constexpr (EPI == EPI_KV) {
                    if (col < NC) {   // K half -> [B][H][NTK][D]
                        float v = acc[m][n][j] + bias[col];
                        int h = col >> 6, d = col & 63;
                        outB[(((size_t)b_ * NH + h) * NTK + t_) * ND + d] = (bf16_t)v;
                    } else {          // V half -> [B][H][D][NTK]
                        int c2_ = col - NC;
                        float v = acc[m][n][j] + bias2[c2_];
                        int h = c2_ >> 6, d = c2_ & 63;
                        outB2[(((size_t)b_ * NH + h) * ND + d) * NTK + t_] = (bf16_t)v;
                    }
                }
            }
        }
    }
}

template<int EPI>
__global__ __launch_bounds__(256) void gemm128(
    const bf16_t* __restrict__ A, const bf16_t* __restrict__ Bt,
    const float* __restrict__ bias, const float* __restrict__ bias2,
    float* __restrict__ outF, bf16_t* __restrict__ outB, bf16_t* __restrict__ outB2,
    int M, int N, int K, int p0, int ldo, int gm)
{
    __shared__ bf16_t sm[32768];
    gemm128_body<EPI>(sm, blockIdx.x, gridDim.x, A, Bt, bias, bias2,
                      outF, outB, outB2, M, N, K, p0, ldo, gm);
}

// Fused Q + KV projection: blocks [0,256) Q-GEMM, [256,832) KV-GEMM.
__global__ __launch_bounds__(256) void qkv_fused(
    const bf16_t* __restrict__ hbuf, const bf16_t* __restrict__ kvbuf,
    const bf16_t* __restrict__ wtq, const bf16_t* __restrict__ wtkv,
    const float* __restrict__ bq, const float* __restrict__ bk,
    const float* __restrict__ bv,
    bf16_t* __restrict__ qbuf, bf16_t* __restrict__ kbuf, bf16_t* __restrict__ vtbuf)
{
    __shared__ bf16_t sm[32768];
    if (blockIdx.x < 256) {
        gemm128_body<EPI_QKV>(sm, blockIdx.x, 256, hbuf, wtq, bq, nullptr,
                              nullptr, qbuf, nullptr, NB * NT, NC, NC, NT, 0, 8);
    } else {
        gemm128_body<EPI_KV>(sm, blockIdx.x - 256, 576, kvbuf, wtkv, bk, bv,
                             nullptr, kbuf, vtbuf, NB * NTK, 2 * NC, NC, NTK, 0, 6);
    }
}

// ---------------------------------------------------------------------------
// Legacy 128x128/BK=32 GEMM (only for tiny m2 GEMM).
// ---------------------------------------------------------------------------
template<int EPI>
__global__ __launch_bounds__(256) void gemm_bt(
    const bf16_t* __restrict__ A, const bf16_t* __restrict__ Bt,
    const float* __restrict__ bias, const float* __restrict__ bias2,
    float* __restrict__ outF, bf16_t* __restrict__ outB, bf16_t* __restrict__ outB2,
    int M, int N, int K, int p0, int ldo, int gm)
{
    __shared__ bf16_t lA[128 * 32];
    __shared__ bf16_t lB[128 * 32];
    const int tid = threadIdx.x;
    const int nwg = gridDim.x;
    const int bid = blockIdx.x;
    const int xcd = bid & 7, base = bid >> 3;
    const int qq = nwg >> 3, rr = nwg & 7;
    int wg = (xcd < rr ? xcd * (qq + 1) : rr * (qq + 1) + (xcd - rr) * qq) + base;
    const int nnt = N >> 7;
    const int gsz = gm * nnt;
    const int g = wg / gsz, r2 = wg - g * gsz;
    const int ntl = r2 / gm, mt = g * gm + (r2 - ntl * gm);
    const int bm = mt * 128, bn = ntl * 128;
    const bf16_t* Ab = A + (size_t)bm * K;
    const bf16_t* Bb = Bt + (size_t)bn * K;
    const int wave = tid >> 6, lane = tid & 63;
    const int wr = wave >> 1, wc = wave & 1;
    const int lr = lane & 15, lk = lane >> 4;
    f32x4 acc[4][4] = {};
    const int nk = K >> 5;
    const int c1 = tid, c2 = tid + 256;
    for (int kt = 0; kt < nk; ++kt) {
        __syncthreads();
        const bf16_t* Abk = Ab + kt * 32;
        const bf16_t* Bbk = Bb + kt * 32;
        GLOAD_LDS16(Abk + (size_t)(c1 >> 2) * K + (c1 & 3) * 8, (char*)lA + c1 * 16);
        GLOAD_LDS16(Abk + (size_t)(c2 >> 2) * K + (c2 & 3) * 8, (char*)lA + c2 * 16);
        GLOAD_LDS16(Bbk + (size_t)(c1 >> 2) * K + (c1 & 3) * 8, (char*)lB + c1 * 16);
        GLOAD_LDS16(Bbk + (size_t)(c2 >> 2) * K + (c2 & 3) * 8, (char*)lB + c2 * 16);
        __syncthreads();
        bf16x8 af[4], bfr[4];
        #pragma unroll
        for (int m = 0; m < 4; ++m)
            af[m] = *(const bf16x8*)&lA[(wr * 64 + m * 16 + lr) * 32 + lk * 8];
        #pragma unroll
        for (int n = 0; n < 4; ++n)
            bfr[n] = *(const bf16x8*)&lB[(wc * 64 + n * 16 + lr) * 32 + lk * 8];
        #pragma unroll
        for (int m = 0; m < 4; ++m)
            #pragma unroll
            for (int n = 0; n < 4; ++n)
                acc[m][n] = __builtin_amdgcn_mfma_f32_16x16x32_bf16(af[m], bfr[n], acc[m][n], 0, 0, 0);
    }
    #pragma unroll
    for (int m = 0; m < 4; ++m) {
        #pragma unroll
        for (int j = 0; j < 4; ++j) {
            const int row = bm + wr * 64 + m * 16 + lk * 4 + j;
            #pragma unroll
            for (int n = 0; n < 4; ++n) {
                const int col = bn + wc * 64 + n * 16 + lr;
                if constexpr (EPI == EPI_F32) {
                    float v = acc[m][n][j] + bias[col];
                    __builtin_nontemporal_store(v, &outF[(size_t)row * ldo + col]);
                }
            }
        }
    }
}

// ---------------------------------------------------------------------------
// Transpose+cast body
// ---------------------------------------------------------------------------
__device__ __forceinline__ void tc_body(
    const float* __restrict__ W, bf16_t* __restrict__ Wt,
    int K, int N, int k0, int n0, int t)
{
    __shared__ float tile[64][65];
    #pragma unroll
    for (int i = 0; i < 4; ++i) {
        const int idx = t + i * 256;
        const int r = idx >> 4, c4 = (idx & 15) << 2;
        const float4 v = *(const float4*)(W + (size_t)(k0 + r) * N + n0 + c4);
        tile[r][c4 + 0] = v.x; tile[r][c4 + 1] = v.y;
        tile[r][c4 + 2] = v.z; tile[r][c4 + 3] = v.w;
    }
    __syncthreads();
    #pragma unroll
    for (int i = 0; i < 4; ++i) {
        const int idx = t + i * 256;
        const int r = idx >> 4, c4 = (idx & 15) << 2;
        bf16x4 o = {(bf16_t)tile[c4 + 0][r], (bf16_t)tile[c4 + 1][r],
                    (bf16_t)tile[c4 + 2][r], (bf16_t)tile[c4 + 3][r]};
        *(bf16x4*)(Wt + (size_t)(n0 + r) * K + k0 + c4) = o;
    }
}

__global__ __launch_bounds__(256) void transpose_cast(
    const float* __restrict__ W, bf16_t* __restrict__ Wt, int K, int N)
{
    tc_body(W, Wt, K, N, blockIdx.x << 6, blockIdx.y << 6, threadIdx.x);
}

// ---------------------------------------------------------------------------
// LN body (ln1 + x->kv cast, MODE-3 semantics), used by prep_layer.
// ---------------------------------------------------------------------------
__device__ __forceinline__ void ln3_body(
    int row, const float* __restrict__ X, const float* __restrict__ sw,
    const float* __restrict__ bw, bf16_t* __restrict__ outB,
    bf16_t* __restrict__ outB2)
{
    const int t = threadIdx.x;
    const float4 v = ((const float4*)(X + (size_t)row * NC))[t];
    float s1 = v.x + v.y + v.z + v.w;
    float s2 = v.x * v.x + v.y * v.y + v.z * v.z + v.w * v.w;
    #pragma unroll
    for (int off = 32; off > 0; off >>= 1) { s1 += __shfl_xor(s1, off); s2 += __shfl_xor(s2, off); }
    __shared__ float rs1[4], rs2[4];
    if ((t & 63) == 0) { rs1[t >> 6] = s1; rs2[t >> 6] = s2; }
    __syncthreads();
    s1 = rs1[0] + rs1[1] + rs1[2] + rs1[3];
    s2 = rs2[0] + rs2[1] + rs2[2] + rs2[3];
    const float mu = s1 * (1.0f / NC);
    const float var = s2 * (1.0f / NC) - mu * mu;
    const float rstd = rsqrtf(var + 1e-6f);
    const int c = t * 4;
    const float4 sv = ((const float4*)sw)[t];
    const float4 bv = ((const float4*)bw)[t];
    float y0 = (v.x - mu) * rstd * sv.x + bv.x;
    float y1 = (v.y - mu) * rstd * sv.y + bv.y;
    float y2 = (v.z - mu) * rstd * sv.z + bv.z;
    float y3 = (v.w - mu) * rstd * sv.w + bv.w;
    bf16x4 o = {(bf16_t)y0, (bf16_t)y1, (bf16_t)y2, (bf16_t)y3};
    *(bf16x4*)(outB + (size_t)row * NC + c) = o;
    const int b_ = row >> 10, t_ = row & 1023;
    bf16x4 o2 = {(bf16_t)v.x, (bf16_t)v.y, (bf16_t)v.z, (bf16_t)v.w};
    *(bf16x4*)(outB2 + ((size_t)b_ * NTK + NO + t_) * NC + c) = o2;
}

// Fused per-layer prep: blocks [0,3072) transpose 6 weights (JIT),
// blocks [3072,7168) = ln1 + x->kv cast. Independent work, one launch.
__global__ __launch_bounds__(256) void prep_layer(
    const float* __restrict__ Wq, const float* __restrict__ Wk,
    const float* __restrict__ Wv, const float* __restrict__ Wo,
    const float* __restrict__ W1, const float* __restrict__ W2,
    bf16_t* __restrict__ wtq, bf16_t* __restrict__ wtkv,
    bf16_t* __restrict__ wto, bf16_t* __restrict__ wt1, bf16_t* __restrict__ wt2,
    const float* __restrict__ X, const float* __restrict__ ln1s,
    const float* __restrict__ ln1b, bf16_t* __restrict__ hbuf,
    bf16_t* __restrict__ kvbuf)
{
    const int bid = blockIdx.x;
    if (bid >= 3072) {
        ln3_body(bid - 3072, X, ln1s, ln1b, hbuf, kvbuf);
        return;
    }
    const float* W; bf16_t* Wt; int K, N, k0, n0;
    if (bid < 1024) {
        const int which = bid >> 8, r = bid & 255;
        K = NC; N = NC;
        k0 = (r & 15) << 6; n0 = (r >> 4) << 6;
        W  = (which == 0) ? Wq : (which == 1) ? Wk : (which == 2) ? Wv : Wo;
        Wt = (which == 0) ? wtq : (which == 1) ? wtkv
           : (which == 2) ? (wtkv + (size_t)NC * NC) : wto;
    } else if (bid < 2048) {
        const int r = bid - 1024;
        K = NC; N = 4 * NC;
        k0 = (r & 15) << 6; n0 = (r >> 4) << 6;
        W = W1; Wt = wt1;
    } else {
        const int r = bid - 2048;
        K = 4 * NC; N = NC;
        k0 = (r & 63) << 6; n0 = (r >> 6) << 6;
        W = W2; Wt = wt2;
    }
    tc_body(W, Wt, K, N, k0, n0, threadIdx.x);
}

// ---------------------------------------------------------------------------
// LayerNorm over C=1024. MODE 0: bf16 natural; 1: kv-m2 row remap.
// ---------------------------------------------------------------------------
template<int MODE>
__global__ __launch_bounds__(256) void ln_row(
    const float* __restrict__ X, const float* __restrict__ sw,
    const float* __restrict__ bw, float* __restrict__ outF,
    bf16_t* __restrict__ outB, bf16_t* __restrict__ outB2)
{
    const int row = blockIdx.x;
    const int t = threadIdx.x;
    const float4 v = ((const float4*)(X + (size_t)row * NC))[t];
    float s1 = v.x + v.y + v.z + v.w;
    float s2 = v.x * v.x + v.y * v.y + v.z * v.z + v.w * v.w;
    #pragma unroll
    for (int off = 32; off > 0; off >>= 1) { s1 += __shfl_xor(s1, off); s2 += __shfl_xor(s2, off); }
    __shared__ float rs1[4], rs2[4];
    if ((t & 63) == 0) { rs1[t >> 6] = s1; rs2[t >> 6] = s2; }
    __syncthreads();
    s1 = rs1[0] + rs1[1] + rs1[2] + rs1[3];
    s2 = rs2[0] + rs2[1] + rs2[2] + rs2[3];
    const float mu = s1 * (1.0f / NC);
    const float var = s2 * (1.0f / NC) - mu * mu;
    const float rstd = rsqrtf(var + 1e-6f);
    const int c = t * 4;
    const float4 sv = ((const float4*)sw)[t];
    const float4 bv = ((const float4*)bw)[t];
    float y0 = (v.x - mu) * rstd * sv.x + bv.x;
    float y1 = (v.y - mu) * rstd * sv.y + bv.y;
    float y2 = (v.z - mu) * rstd * sv.z + bv.z;
    float y3 = (v.w - mu) * rstd * sv.w + bv.w;
    size_t dst;
    if constexpr (MODE == 1) dst = ((size_t)(row / NO) * NTK + (row % NO)) * NC + c;
    else dst = (size_t)row * NC + c;
    bf16x4 o = {(bf16_t)y0, (bf16_t)y1, (bf16_t)y2, (bf16_t)y3};
    *(bf16x4*)(outB + dst) = o;
}

// ---------------------------------------------------------------------------
// Final LN fused with mask-cast + new_mem extraction.
// ---------------------------------------------------------------------------
__global__ __launch_bounds__(256) void ln_final(
    const float* __restrict__ X, const float* __restrict__ sw,
    const float* __restrict__ bw, const int* __restrict__ tokens,
    bf16_t* __restrict__ xm, float* __restrict__ outMem)
{
    const int row = blockIdx.x;
    const int t = threadIdx.x;
    const float4 v = ((const float4*)(X + (size_t)row * NC))[t];
    float s1 = v.x + v.y + v.z + v.w;
    float s2 = v.x * v.x + v.y * v.y + v.z * v.z + v.w * v.w;
    #pragma unroll
    for (int off = 32; off > 0; off >>= 1) { s1 += __shfl_xor(s1, off); s2 += __shfl_xor(s2, off); }
    __shared__ float rs1[4], rs2[4];
    if ((t & 63) == 0) { rs1[t >> 6] = s1; rs2[t >> 6] = s2; }
    __syncthreads();
    s1 = rs1[0] + rs1[1] + rs1[2] + rs1[3];
    s2 = rs2[0] + rs2[1] + rs2[2] + rs2[3];
    const float mu = s1 * (1.0f / NC);
    const float var = s2 * (1.0f / NC) - mu * mu;
    const float rstd = rsqrtf(var + 1e-6f);
    const int c = t * 4;
    const float4 sv = ((const float4*)sw)[t];
    const float4 bv = ((const float4*)bw)[t];
    float y0 = (v.x - mu) * rstd * sv.x + bv.x;
    float y1 = (v.y - mu) * rstd * sv.y + bv.y;
    float y2 = (v.z - mu) * rstd * sv.z + bv.z;
    float y3 = (v.w - mu) * rstd * sv.w + bv.w;
    const bool ok = tokens[row] != 0;
    bf16x4 o;
    if (ok) { o = (bf16x4){(bf16_t)y0, (bf16_t)y1, (bf16_t)y2, (bf16_t)y3}; }
    else    { o = (bf16x4){(bf16_t)0.f, (bf16_t)0.f, (bf16_t)0.f, (bf16_t)0.f}; }
    *(bf16x4*)(xm + (size_t)row * NC + c) = o;
    const int b_ = row >> 10, t_ = row & 1023;
    if (t_ >= NT - NO) {
        float4 f; f.x = y0; f.y = y1; f.z = y2; f.w = y3;
        *(float4*)(outMem + ((size_t)b_ * NO + (t_ - (NT - NO))) * NC + c) = f;
    }
}

// ---------------------------------------------------------------------------
// Flash attention: 32 q-rows per wave, 4 waves/block, no barriers, 64-key
// tiles, LPT y-order. Softmax in exp2 domain (scale folds log2(e)) so every
// exponential is a single v_exp_f32 — softmax(x) preserved exactly.
// ---------------------------------------------------------------------------
#define QKSCALE 0.1803368801111204f   // 0.125 * log2(e)

__global__ __launch_bounds__(256) void attn_kernel(
    const bf16_t* __restrict__ Q, const bf16_t* __restrict__ Kb,
    const bf16_t* __restrict__ Vt, const int* __restrict__ tokens,
    bf16_t* __restrict__ Ob)
{
    const int bh = blockIdx.x;
    const int b = bh >> 4, h = bh & 15;
    const int w = threadIdx.x >> 6;
    const int lane = threadIdx.x & 63;
    const int yt = gridDim.y - 1 - blockIdx.y;   // LPT: long tiles first
    const int q0 = (yt << 7) + (w << 5);
    const int lr = lane & 15, lk = lane >> 4;
    const bf16_t* Qp = Q + ((size_t)bh * NT + q0) * ND;
    bf16x8 qf[2][2];
    #pragma unroll
    for (int qs = 0; qs < 2; ++qs) {
        qf[qs][0] = *(const bf16x8*)(Qp + (qs * 16 + lr) * ND + lk * 8);
        qf[qs][1] = *(const bf16x8*)(Qp + (qs * 16 + lr) * ND + 32 + lk * 8);
    }
    const bf16_t* Kbase = Kb + (size_t)bh * NTK * ND;
    const bf16_t* Vbase = Vt + (size_t)bh * ND * NTK;
    const int* tokb = tokens + b * NT;
    float mrow[2][4] = {{-1e30f, -1e30f, -1e30f, -1e30f}, {-1e30f, -1e30f, -1e30f, -1e30f}};
    float lsum[2][4] = {};
    f32x4 acc[2][4] = {};
    __shared__ bf16_t pb[4][2][16 * 64];
    const int kmax = NO + q0 + 32;
    for (int k0 = 0; k0 < kmax; k0 += 64) {
        f32x4 st[2][4] = {};
        __builtin_amdgcn_s_setprio(1);
        #pragma unroll
        for (int nt = 0; nt < 4; ++nt) {
            const bf16_t* Kp = Kbase + (size_t)(k0 + nt * 16 + lr) * ND + lk * 8;
            bf16x8 kf0 = *(const bf16x8*)(Kp);
            bf16x8 kf1 = *(const bf16x8*)(Kp + 32);
            #pragma unroll
            for (int qs = 0; qs < 2; ++qs) {
                st[qs][nt] = __builtin_amdgcn_mfma_f32_16x16x32_bf16(qf[qs][0], kf0, st[qs][nt], 0, 0, 0);
                st[qs][nt] = __builtin_amdgcn_mfma_f32_16x16x32_bf16(qf[qs][1], kf1, st[qs][nt], 0, 0, 0);
            }
        }
        __builtin_amdgcn_s_setprio(0);
        #pragma unroll
        for (int qs = 0; qs < 2; ++qs) {
            char* pbq = (char*)pb[w][qs];
            float sc[4][4];
            float tmax[4] = {-1e30f, -1e30f, -1e30f, -1e30f};
            #pragma unroll
            for (int nt = 0; nt < 4; ++nt) {
                const int key = k0 + nt * 16 + lr;
                const int kt = key - NO;
                const int kts = kt < 0 ? 0 : kt;
                const bool keyok = (kt < 0) | (tokb[kts] != 0);
                #pragma unroll
                for (int j = 0; j < 4; ++j) {
                    const int qrow = q0 + qs * 16 + lk * 4 + j;
                    const bool ok = keyok && (kt <= qrow);
                    const float s = ok ? st[qs][nt][j] * QKSCALE : -1e9f;
                    sc[nt][j] = s;
                    tmax[j] = fmaxf(tmax[j], s);
                }
            }
            #pragma unroll
            for (int off = 1; off < 16; off <<= 1)
                #pragma unroll
                for (int j = 0; j < 4; ++j) tmax[j] = fmaxf(tmax[j], __shfl_xor(tmax[j], off));
            float resc[4], p[4][4], psum[4] = {0.f, 0.f, 0.f, 0.f};
            #pragma unroll
            for (int j = 0; j < 4; ++j) {
                const float mnew = fmaxf(mrow[qs][j], tmax[j]);
                resc[j] = EXP2F(mrow[qs][j] - mnew);
                mrow[qs][j] = mnew;
            }
            #pragma unroll
            for (int nt = 0; nt < 4; ++nt)
                #pragma unroll
                for (int j = 0; j < 4; ++j) { p[nt][j] = EXP2F(sc[nt][j] - mrow[qs][j]); psum[j] += p[nt][j]; }
            #pragma unroll
            for (int off = 1; off < 16; off <<= 1)
                #pragma unroll
                for (int j = 0; j < 4; ++j) psum[j] += __shfl_xor(psum[j], off);
            #pragma unroll
            for (int j = 0; j < 4; ++j) lsum[qs][j] = lsum[qs][j] * resc[j] + psum[j];
            #pragma unroll
            for (int dt = 0; dt < 4; ++dt)
                #pragma unroll
                for (int j = 0; j < 4; ++j) acc[qs][dt][j] *= resc[j];
            #pragma unroll
            for (int nt = 0; nt < 4; ++nt)
                #pragma unroll
                for (int j = 0; j < 4; ++j) {
                    const int row = lk * 4 + j;
                    const int byt = (row << 7) + ((((nt << 4) + lr) << 1) ^ ((row & 7) << 4));
                    *(bf16_t*)(pbq + byt) = (bf16_t)p[nt][j];
                }
        }
        const int swz = (lr & 7) << 4;
        bf16x8 pa[2][2];
        #pragma unroll
        for (int qs = 0; qs < 2; ++qs) {
            const char* pbq = (const char*)pb[w][qs];
            pa[qs][0] = *(const bf16x8*)(pbq + ((lr << 7) + (((lk << 4)) ^ swz)));
            pa[qs][1] = *(const bf16x8*)(pbq + ((lr << 7) + ((64 + (lk << 4)) ^ swz)));
        }
        __builtin_amdgcn_s_setprio(1);
        #pragma unroll
        for (int dt = 0; dt < 4; ++dt) {
            const bf16_t* Vp = Vbase + (size_t)(dt * 16 + lr) * NTK + k0 + lk * 8;
            bf16x8 vf0 = *(const bf16x8*)(Vp);
            bf16x8 vf1 = *(const bf16x8*)(Vp + 32);
            #pragma unroll
            for (int qs = 0; qs < 2; ++qs) {
                acc[qs][dt] = __builtin_amdgcn_mfma_f32_16x16x32_bf16(pa[qs][0], vf0, acc[qs][dt], 0, 0, 0);
                acc[qs][dt] = __builtin_amdgcn_mfma_f32_16x16x32_bf16(pa[qs][1], vf1, acc[qs][dt], 0, 0, 0);
            }
        }
        __builtin_amdgcn_s_setprio(0);
    }
    #pragma unroll
    for (int qs = 0; qs < 2; ++qs)
        #pragma unroll
        for (int dt = 0; dt < 4; ++dt)
            #pragma unroll
            for (int j = 0; j < 4; ++j)
                Ob[((size_t)b * NT + q0 + qs * 16 + lk * 4 + j) * NC + h * ND + dt * 16 + lr] =
                    (bf16_t)(acc[qs][dt][j] / lsum[qs][j]);
}

// ---------------------------------------------------------------------------
// Small kernels
// ---------------------------------------------------------------------------
__global__ __launch_bounds__(256) void sum_proj_kernel(
    const float* __restrict__ ssum, const float* __restrict__ sumw,
    const float* __restrict__ alpha, float* __restrict__ add)
{
    const int b = blockIdx.y;
    const int c = blockIdx.x * 256 + threadIdx.x;
    float a = 0.f;
    for (int k = 0; k < NC; ++k) a += ssum[b * NC + k] * sumw[(size_t)k * NC + c];
    add[b * NC + c] = a * sigmoidf_(alpha[c]);
}

__global__ __launch_bounds__(256) void embed_kernel(
    const int* __restrict__ tokens, const int* __restrict__ posoff,
    const float* __restrict__ tokw, const float* __restrict__ posw,
    const float* __restrict__ add, float* __restrict__ X)
{
    const int bt = blockIdx.x;
    const int b = bt >> 10, t = bt & 1023;
    const int c = threadIdx.x * 4;
    const int tok = tokens[bt];
    int p = t + posoff[0];
    p = p < 0 ? 0 : (p > NS - 1 ? NS - 1 : p);
    const float4 tv = *(const float4*)(tokw + (size_t)tok * NC + c);
    const float4 pv = *(const float4*)(posw + (size_t)p * NC + c);
    const float4 av = *(const float4*)(add + b * NC + c);
    float4 o;
    o.x = tv.x + pv.x + av.x; o.y = tv.y + pv.y + av.y;
    o.z = tv.z + pv.z + av.z; o.w = tv.w + pv.w + av.w;
    *(float4*)(X + (size_t)bt * NC + c) = o;
}

__global__ __launch_bounds__(256) void cast_f32_bf16_kernel(
    const float* __restrict__ in, bf16_t* __restrict__ out)
{
    const size_t i = ((size_t)blockIdx.x * 256 + threadIdx.x) * 4;
    const float4 v = *(const float4*)(in + i);
    bf16x4 o = {(bf16_t)v.x, (bf16_t)v.y, (bf16_t)v.z, (bf16_t)v.w};
    *(bf16x4*)(out + i) = o;
}

__global__ __launch_bounds__(256) void sumpart_kernel(
    const bf16_t* __restrict__ XM, float* __restrict__ sbuf)
{
    const int b = blockIdx.z;
    const int c = blockIdx.x * 256 + threadIdx.x;
    const int t0 = blockIdx.y * 64;
    float a = 0.f;
    for (int t = t0; t < t0 + 64; ++t)
        a += (float)XM[((size_t)b * NT + t) * NC + c];
    atomicAdd(&sbuf[b * NC + c], a);
}

__global__ __launch_bounds__(256) void ssum_out_kernel(
    const float* __restrict__ sbuf, const int* __restrict__ tokens,
    const float* __restrict__ ssum, const float* __restrict__ lamp, float* __restrict__ out)
{
    const int b = blockIdx.y;
    const int c = blockIdx.x * 256 + threadIdx.x;
    int cnt = 0;
    for (int t = 0; t < NT; ++t) cnt += (tokens[b * NT + t] != 0);
    const float summary = sbuf[b * NC + c] / ((float)cnt + 1e-6f);
    const float lam = sigmoidf_(lamp[c]);
    out[b * NC + c] = ssum[b * NC + c] * lam + summary * (1.0f - lam);
}

// ---------------------------------------------------------------------------
extern "C" void kernel_launch(void* const* d_in, const int* in_sizes, int n_in,
                              void* d_out, int out_size, void* d_ws, size_t ws_size,
                              hipStream_t stream)
{
    (void)in_sizes; (void)n_in; (void)out_size; (void)ws_size;
    const int*   tokens   = (const int*)d_in[0];
    const int*   posoff   = (const int*)d_in[1];
    const float* mem      = (const float*)d_in[2];
    const float* ssum     = (const float*)d_in[3];
    const float* tok_emb  = (const float*)d_in[4];
    const float* pos_emb  = (const float*)d_in[5];
    const float* mem_w    = (const float*)d_in[6];
    const float* mem_b    = (const float*)d_in[7];
    const float* memln_s  = (const float*)d_in[8];
    const float* memln_b  = (const float*)d_in[9];
    const float* alpha_p  = (const float*)d_in[10];
    const float* sum_w    = (const float*)d_in[11];
    const float* ln1_s    = (const float*)d_in[12];
    const float* ln1_b    = (const float*)d_in[13];
    const float* Wq       = (const float*)d_in[14];
    const float* bq       = (const float*)d_in[15];
    const float* Wk       = (const float*)d_in[16];
    const float* bk       = (const float*)d_in[17];
    const float* Wv       = (const float*)d_in[18];
    const float* bv       = (const float*)d_in[19];
    const float* Wo       = (const float*)d_in[20];
    const float* bo       = (const float*)d_in[21];
    const float* ln2_s    = (const float*)d_in[22];
    const float* ln2_b    = (const float*)d_in[23];
    const float* W1       = (const float*)d_in[24];
    const float* b1       = (const float*)d_in[25];
    const float* W2       = (const float*)d_in[26];
    const float* b2       = (const float*)d_in[27];
    const float* fln_s    = (const float*)d_in[28];
    const float* fln_b    = (const float*)d_in[29];
    const float* head_w   = (const float*)d_in[30];
    const float* head_b   = (const float*)d_in[31];
    const float* lam_p    = (const float*)d_in[32];

    float* out_mem    = (float*)d_out;                          // B*O*C
    float* out_ssum   = out_mem + (size_t)NB * NO * NC;         // B*C
    float* out_logits = out_ssum + (size_t)NB * NC;             // B*T*V

    char* wp = (char*)d_ws;
    auto alloc = [&](size_t bytes) { char* p = wp; wp += (bytes + 255) & ~(size_t)255; return p; };
    bf16_t* wt_head = (bf16_t*)alloc((size_t)NV * NC * 2);
    bf16_t* wt_mem  = (bf16_t*)alloc((size_t)NC * NC * 2);
    bf16_t* wt_q    = (bf16_t*)alloc((size_t)NC * NC * 2);
    bf16_t* wt_kv   = (bf16_t*)alloc((size_t)2 * NC * NC * 2);
    bf16_t* wt_o    = (bf16_t*)alloc((size_t)NC * NC * 2);
    bf16_t* wt_1    = (bf16_t*)alloc((size_t)NC * 4 * NC * 2);
    bf16_t* wt_2    = (bf16_t*)alloc((size_t)NC * 4 * NC * 2);
    float*  xbuf    = (float*)alloc((size_t)NB * NT * NC * 4);
    bf16_t* hbuf    = (bf16_t*)alloc((size_t)NB * NT * NC * 2);
    bf16_t* kvbuf   = (bf16_t*)alloc((size_t)NB * NTK * NC * 2);
    bf16_t* qbuf    = (bf16_t*)alloc((size_t)NB * NT * NC * 2);
    bf16_t* kbuf    = (bf16_t*)alloc((size_t)NB * NTK * NC * 2);
    bf16_t* vtbuf   = (bf16_t*)alloc((size_t)NB * NTK * NC * 2);
    bf16_t* obuf    = (bf16_t*)alloc((size_t)NB * NT * NC * 2);
    bf16_t* midbuf  = (bf16_t*)alloc((size_t)NB * NT * 4 * NC * 2);
    bf16_t* xmbuf   = (bf16_t*)alloc((size_t)NB * NT * NC * 2);
    bf16_t* membf   = (bf16_t*)alloc((size_t)NB * NO * NC * 2);
    float*  m2f     = (float*)alloc((size_t)NB * NO * NC * 4);
    float*  addb    = (float*)alloc((size_t)NB * NC * 4);
    float*  sbuf    = (float*)alloc((size_t)NB * NC * 4);

    (void)hipMemsetAsync(sbuf, 0, (size_t)NB * NC * 4, stream);

    // weight transposes (head + mem)
    transpose_cast<<<dim3(NC / 64, NV / 64), 256, 0, stream>>>(head_w, wt_head, NC, NV);
    transpose_cast<<<dim3(NC / 64, NC / 64), 256, 0, stream>>>(mem_w, wt_mem, NC, NC);

    // m2 = LN(mem @ mem_w + mem_b) -> kv rows [0,O)
    cast_f32_bf16_kernel<<<(NB * NO * NC) / 1024, 256, 0, stream>>>(mem, membf);
    gemm_bt<EPI_F32><<<32, 256, 0, stream>>>(
        membf, wt_mem, mem_b, nullptr, m2f, nullptr, nullptr, NB * NO, NC, NC, 0, NC, 4);
    ln_row<1><<<NB * NO, 256, 0, stream>>>(m2f, memln_s, memln_b, nullptr, kvbuf, nullptr);

    // x = tok_emb[tokens] + pos_emb + (ssum @ sum_w)*sigmoid(alpha)
    sum_proj_kernel<<<dim3(NC / 256, NB), 256, 0, stream>>>(ssum, sum_w, alpha_p, addb);
    embed_kernel<<<NB * NT, 256, 0, stream>>>(tokens, posoff, tok_emb, pos_emb, addb, xbuf);

    for (int i = 0; i < NL; ++i) {
        // fused: JIT weight transposes + (ln1 + x->kv cast), one launch
        prep_layer<<<7168, 256, 0, stream>>>(
            Wq + (size_t)i * NC * NC, Wk + (size_t)i * NC * NC,
            Wv + (size_t)i * NC * NC, Wo + (size_t)i * NC * NC,
            W1 + (size_t)i * NC * 4 * NC, W2 + (size_t)i * 4 * NC * NC,
            wt_q, wt_kv, wt_o, wt_1, wt_2,
            xbuf, ln1_s + i * NC, ln1_b + i * NC, hbuf, kvbuf);

        // Q + KV projections fused into ONE launch (832 blocks)
        qkv_fused<<<832, 256, 0, stream>>>(
            hbuf, kvbuf, wt_q, wt_kv, bq + i * NC, bk + i * NC, bv + i * NC,
            qbuf, kbuf, vtbuf);

        attn_kernel<<<dim3(NB * NH, NT / 128), 256, 0, stream>>>(qbuf, kbuf, vtbuf, tokens, obuf);

        gemm128<EPI_ADD><<<256, 256, 0, stream>>>(
            obuf, wt_o, bo + i * NC, nullptr, xbuf, nullptr, nullptr, NB * NT, NC, NC, 0, NC, 8);

        ln_row<0><<<NB * NT, 256, 0, stream>>>(xbuf, ln2_s + i * NC, ln2_b + i * NC, nullptr, hbuf, nullptr);
        // FFN1: 256^2 engine (GELU epilogue)
        gemm8p<1><<<256, 512, 0, stream>>>(
            hbuf, wt_1, b1 + (size_t)i * 4 * NC, nullptr, midbuf, NB * NT, 4 * NC, NC, 4 * NC, 4);
        // FFN2
        gemm128<EPI_ADD><<<256, 256, 0, stream>>>(
            midbuf, wt_2, b2 + i * NC, nullptr, xbuf, nullptr, nullptr, NB * NT, NC, 4 * NC, 0, NC, 8);
    }

    // final LN fused with mask-cast + new_mem extraction
    ln_final<<<NB * NT, 256, 0, stream>>>(xbuf, fln_s, fln_b, tokens, xmbuf, out_mem);
    sumpart_kernel<<<dim3(NC / 256, NT / 64, NB), 256, 0, stream>>>(xmbuf, sbuf);
    ssum_out_kernel<<<dim3(NC / 256, NB), 256, 0, stream>>>(sbuf, tokens, ssum, lam_p, out_ssum);
    // head: 256^2 engine
    gemm8p<0><<<2000, 512, 0, stream>>>(
        xmbuf, wt_head, head_b, out_logits, nullptr, NB * NT, NV, NC, NV, 4);
}

// Round 17
// 1618.534 us; speedup vs baseline: 1.1273x; 1.0240x over previous
//
#include <hip/hip_runtime.h>
#include <hip/hip_bf16.h>

typedef __bf16 bf16_t;
typedef __bf16 bf16x8 __attribute__((ext_vector_type(8)));
typedef __bf16 bf16x4 __attribute__((ext_vector_type(4)));
typedef float f32x4 __attribute__((ext_vector_type(4)));

#define NB 4
#define NT 1024
#define NO 128
#define NC 1024
#define NH 16
#define NL 4
#define NV 32000
#define NS 4096
#define ND 64
#define NTK (NO + NT)   // 1152

#define GLOAD_LDS16(g, l) __builtin_amdgcn_global_load_lds( \
    (__attribute__((address_space(1))) void*)(g), \
    (__attribute__((address_space(3))) void*)(l), 16, 0, 0)

#define EXP2F(x) __builtin_amdgcn_exp2f(x)

__device__ __forceinline__ float sigmoidf_(float x) { return 1.0f / (1.0f + __expf(-x)); }

#define EPI_F32  0
#define EPI_ADD  1
#define EPI_GELU 2
#define EPI_QKV  3
#define EPI_KV   4

// ---------------------------------------------------------------------------
// 8-wave 256x256 GEMM (round-6 engine): BK=64, 512 thr, double-buffered
// 128KB LDS, counted vmcnt, raw s_barrier, XOR swizzle, fragment reuse.
// EPI 0: f32 nontemporal; 1: GELU->bf16.
// ---------------------------------------------------------------------------
template<int EPI>
__global__ __launch_bounds__(512) void gemm8p(
    const bf16_t* __restrict__ A, const bf16_t* __restrict__ Bt,
    const float* __restrict__ bias, float* __restrict__ outF,
    bf16_t* __restrict__ outB, int M, int N, int K, int ldo, int gm)
{
    __shared__ bf16_t sm[65536];
    const int tid = threadIdx.x;
    const int w = tid >> 6, lane = tid & 63;
    const int wr = w >> 2, wc = w & 3;
    const int lr = lane & 15, lk = lane >> 4;
    const int nwg = gridDim.x;
    const int bid = blockIdx.x;
    const int xcd = bid & 7, base = bid >> 3;
    const int qq = nwg >> 3, rr = nwg & 7;
    int wg = (xcd < rr ? xcd * (qq + 1) : rr * (qq + 1) + (xcd - rr) * qq) + base;
    const int nnt = N >> 8;
    const int gsz = gm * nnt;
    const int g = wg / gsz, r2 = wg - g * gsz;
    const int ntl = r2 / gm, mt = g * gm + (r2 - ntl * gm);
    const int bm = mt << 8, bn = ntl << 8;
    const bf16_t* Ab = A + (size_t)bm * K;
    const bf16_t* Bb = Bt + (size_t)bn * K;
    const int srow = tid >> 3;
    const int scol = ((tid & 7) ^ (srow & 7)) << 3;
    const int nk = K >> 6;
    f32x4 acc[8][4] = {};

    auto STAGE = [&](int b, int kt, int h) {
        const bf16_t* gsrc = (h < 2) ? Ab : Bb;
        const int half = h & 1;
        char* lbase = (char*)(sm + ((h < 2) ? 0 : 32768) + b * 16384 + half * 8192);
        #pragma unroll
        for (int i = 0; i < 2; ++i) {
            GLOAD_LDS16(gsrc + (size_t)(half * 128 + i * 64 + srow) * K + kt * 64 + scol,
                        lbase + (i * 512 + tid) * 16);
        }
    };

    #pragma unroll
    for (int h = 0; h < 4; ++h) STAGE(0, 0, h);
    asm volatile("s_waitcnt vmcnt(0)" ::: "memory");
    __builtin_amdgcn_s_barrier();

    for (int kt = 0; kt < nk; ++kt) {
        const int curb = kt & 1;
        const bool dostage = (kt + 1) < nk;
        const char* Abase = (const char*)(sm + curb * 16384);
        const char* Bbase = (const char*)(sm + 32768 + curb * 16384);

        if (dostage) {
            STAGE(curb ^ 1, kt + 1, 0);
            STAGE(curb ^ 1, kt + 1, 1);
            asm volatile("s_waitcnt vmcnt(4)" ::: "memory");
        } else {
            asm volatile("s_waitcnt vmcnt(0)" ::: "memory");
        }
        __builtin_amdgcn_s_barrier();

        bf16x8 bfr[4][2];
        #pragma unroll
        for (int n = 0; n < 4; ++n)
            #pragma unroll
            for (int ks = 0; ks < 2; ++ks) {
                const int row = wc * 64 + n * 16 + lr;
                bfr[n][ks] = *(const bf16x8*)(Bbase + row * 128 + ((((ks << 2) + lk) ^ (row & 7)) << 4));
            }
        bf16x8 af[4][2];
        #pragma unroll
        for (int m = 0; m < 4; ++m)
            #pragma unroll
            for (int ks = 0; ks < 2; ++ks) {
                const int row = wr * 128 + m * 16 + lr;
                af[m][ks] = *(const bf16x8*)(Abase + row * 128 + ((((ks << 2) + lk) ^ (row & 7)) << 4));
            }
        asm volatile("s_waitcnt lgkmcnt(0)" ::: "memory");
        __builtin_amdgcn_sched_barrier(0);
        __builtin_amdgcn_s_setprio(1);
        #pragma unroll
        for (int m = 0; m < 4; ++m)
            #pragma unroll
            for (int n = 0; n < 4; ++n)
                #pragma unroll
                for (int ks = 0; ks < 2; ++ks)
                    acc[m][n] = __builtin_amdgcn_mfma_f32_16x16x32_bf16(
                        af[m][ks], bfr[n][ks], acc[m][n], 0, 0, 0);
        __builtin_amdgcn_s_setprio(0);

        if (dostage) {
            STAGE(curb ^ 1, kt + 1, 2);
            STAGE(curb ^ 1, kt + 1, 3);
        }
        bf16x8 ag[4][2];
        #pragma unroll
        for (int m = 0; m < 4; ++m)
            #pragma unroll
            for (int ks = 0; ks < 2; ++ks) {
                const int row = wr * 128 + 64 + m * 16 + lr;
                ag[m][ks] = *(const bf16x8*)(Abase + row * 128 + ((((ks << 2) + lk) ^ (row & 7)) << 4));
            }
        asm volatile("s_waitcnt lgkmcnt(0)" ::: "memory");
        __builtin_amdgcn_sched_barrier(0);
        __builtin_amdgcn_s_setprio(1);
        #pragma unroll
        for (int m = 0; m < 4; ++m)
            #pragma unroll
            for (int n = 0; n < 4; ++n)
                #pragma unroll
                for (int ks = 0; ks < 2; ++ks)
                    acc[4 + m][n] = __builtin_amdgcn_mfma_f32_16x16x32_bf16(
                        ag[m][ks], bfr[n][ks], acc[4 + m][n], 0, 0, 0);
        __builtin_amdgcn_s_setprio(0);
        __builtin_amdgcn_s_barrier();
    }

    float bv4[4];
    #pragma unroll
    for (int n = 0; n < 4; ++n) bv4[n] = bias[bn + wc * 64 + n * 16 + lr];
    #pragma unroll
    for (int m = 0; m < 8; ++m) {
        #pragma unroll
        for (int j = 0; j < 4; ++j) {
            const int row = bm + wr * 128 + m * 16 + lk * 4 + j;
            #pragma unroll
            for (int n = 0; n < 4; ++n) {
                const int col = bn + wc * 64 + n * 16 + lr;
                float v = acc[m][n][j] + bv4[n];
                if constexpr (EPI == 0) {
                    __builtin_nontemporal_store(v, &outF[(size_t)row * ldo + col]);
                } else {
                    float u = 1.5957691216057308f * (v + 0.044715f * v * v * v);
                    float g_ = v / (1.0f + __expf(-u));
                    outB[(size_t)row * ldo + col] = (bf16_t)g_;
                }
            }
        }
    }
}

// ---------------------------------------------------------------------------
// 4-wave 128x128 GEMM body (round-6 schedule): BK=64, 256 thr, 64 KB LDS,
// counted vmcnt(4), XOR swizzle, B-frags held across both ks-phases.
// ---------------------------------------------------------------------------
template<int EPI>
__device__ __forceinline__ void gemm128_body(
    bf16_t* sm, int bid, int nwg,
    const bf16_t* __restrict__ A, const bf16_t* __restrict__ Bt,
    const float* __restrict__ bias, const float* __restrict__ bias2,
    float* __restrict__ outF, bf16_t* __restrict__ outB, bf16_t* __restrict__ outB2,
    int M, int N, int K, int p0, int ldo, int gm)
{
    char* smb = (char*)sm;
    const int tid = threadIdx.x;
    const int w = tid >> 6, lane = tid & 63;
    const int wr = w >> 1, wc = w & 1;
    const int lr = lane & 15, lk = lane >> 4;
    const int xcd = bid & 7, base = bid >> 3;
    const int qq = nwg >> 3, rr = nwg & 7;
    int wg = (xcd < rr ? xcd * (qq + 1) : rr * (qq + 1) + (xcd - rr) * qq) + base;
    const int nnt = N >> 7;
    const int gsz = gm * nnt;
    const int g = wg / gsz, r2 = wg - g * gsz;
    const int ntl = r2 / gm, mt = g * gm + (r2 - ntl * gm);
    const int bm = mt << 7, bn = ntl << 7;
    const bf16_t* Ab = A + (size_t)bm * K;
    const bf16_t* Bb = Bt + (size_t)bn * K;
    const int srow = tid >> 3;
    const int scol = ((tid & 7) ^ (srow & 7)) << 3;
    const int nk = K >> 6;
    f32x4 acc[4][4] = {};

    auto STAGE = [&](int b, int kt, int h) {
        const bf16_t* gsrc = h ? Bb : Ab;
        char* lbase = smb + h * 32768 + b * 16384;
        #pragma unroll
        for (int i = 0; i < 4; ++i) {
            GLOAD_LDS16(gsrc + (size_t)(i * 32 + srow) * K + kt * 64 + scol,
                        lbase + (i * 256 + tid) * 16);
        }
    };

    STAGE(0, 0, 0); STAGE(0, 0, 1);
    asm volatile("s_waitcnt vmcnt(0)" ::: "memory");
    __builtin_amdgcn_s_barrier();

    for (int kt = 0; kt < nk; ++kt) {
        const int curb = kt & 1;
        const bool dostage = (kt + 1) < nk;
        const char* Abase = smb + curb * 16384;
        const char* Bbase = smb + 32768 + curb * 16384;

        if (dostage) {
            STAGE(curb ^ 1, kt + 1, 0);
            asm volatile("s_waitcnt vmcnt(4)" ::: "memory");
        } else {
            asm volatile("s_waitcnt vmcnt(0)" ::: "memory");
        }
        __builtin_amdgcn_s_barrier();

        bf16x8 bfr[4][2];
        #pragma unroll
        for (int n = 0; n < 4; ++n)
            #pragma unroll
            for (int ks_ = 0; ks_ < 2; ++ks_) {
                const int row = wc * 64 + n * 16 + lr;
                bfr[n][ks_] = *(const bf16x8*)(Bbase + row * 128 + ((((ks_ << 2) + lk) ^ (row & 7)) << 4));
            }
        bf16x8 af[4];
        #pragma unroll
        for (int m = 0; m < 4; ++m) {
            const int row = wr * 64 + m * 16 + lr;
            af[m] = *(const bf16x8*)(Abase + row * 128 + (((lk) ^ (row & 7)) << 4));
        }
        asm volatile("s_waitcnt lgkmcnt(0)" ::: "memory");
        __builtin_amdgcn_sched_barrier(0);
        __builtin_amdgcn_s_setprio(1);
        #pragma unroll
        for (int m = 0; m < 4; ++m)
            #pragma unroll
            for (int n = 0; n < 4; ++n)
                acc[m][n] = __builtin_amdgcn_mfma_f32_16x16x32_bf16(
                    af[m], bfr[n][0], acc[m][n], 0, 0, 0);
        __builtin_amdgcn_s_setprio(0);

        if (dostage) STAGE(curb ^ 1, kt + 1, 1);
        bf16x8 ag[4];
        #pragma unroll
        for (int m = 0; m < 4; ++m) {
            const int row = wr * 64 + m * 16 + lr;
            ag[m] = *(const bf16x8*)(Abase + row * 128 + (((4 + lk) ^ (row & 7)) << 4));
        }
        asm volatile("s_waitcnt lgkmcnt(0)" ::: "memory");
        __builtin_amdgcn_sched_barrier(0);
        __builtin_amdgcn_s_setprio(1);
        #pragma unroll
        for (int m = 0; m < 4; ++m)
            #pragma unroll
            for (int n = 0; n < 4; ++n)
                acc[m][n] = __builtin_amdgcn_mfma_f32_16x16x32_bf16(
                    ag[m], bfr[n][1], acc[m][n], 0, 0, 0);
        __builtin_amdgcn_s_setprio(0);
        __builtin_amdgcn_s_barrier();
    }

    #pragma unroll
    for (int m = 0; m < 4; ++m) {
        #pragma unroll
        for (int j = 0; j < 4; ++j) {
            const int row = bm + wr * 64 + m * 16 + lk * 4 + j;
            int b_ = 0, t_ = 0;
            if constexpr (EPI == EPI_QKV || EPI == EPI_KV) { b_ = row / p0; t_ = row % p0; }
            #pragma unroll
            for (int n = 0; n < 4; ++n) {
                const int col = bn + wc * 64 + n * 16 + lr;
                if constexpr (EPI == EPI_F32) {
                    float v = acc[m][n][j] + bias[col];
                    __builtin_nontemporal_store(v, &outF[(size_t)row * ldo + col]);
                } else if constexpr (EPI == EPI_ADD) {
                    float v = acc[m][n][j] + bias[col];
                    outF[(size_t)row * ldo + col] += v;
                } else if constexpr (EPI == EPI_GELU) {
                    float v = acc[m][n][j] + bias[col];
                    float u = 1.5957691216057308f * (v + 0.044715f * v * v * v);
                    float g_ = v / (1.0f + __expf(-u));
                    outB[(size_t)row * ldo + col] = (bf16_t)g_;
                } else if constexpr (EPI == EPI_QKV) {
                    float v = acc[m][n][j] + bias[col];
                    int h = col >> 6, d = col & 63;
                    outB[(((size_t)b_ * NH + h) * p0 + t_) * ND + d] = (bf16_t)v;
                } else if constexpr (EPI == EPI_KV) {
                    if (col < NC) {   // K half -> [B][H][NTK][D]
                        float v = acc[m][n][j] + bias[col];
                        int h = col >> 6, d = col & 63;
                        outB[(((size_t)b_ * NH + h) * NTK + t_) * ND + d] = (bf16_t)v;
                    } else {          // V half -> [B][H][D][NTK]
                        int c2_ = col - NC;
                        float v = acc[m][n][j] + bias2[c2_];
                        int h = c2_ >> 6, d = c2_ & 63;
                        outB2[(((size_t)b_ * NH + h) * ND + d) * NTK + t_] = (bf16_t)v;
                    }
                }
            }
        }
    }
}

template<int EPI>
__global__ __launch_bounds__(256) void gemm128(
    const bf16_t* __restrict__ A, const bf16_t* __restrict__ Bt,
    const float* __restrict__ bias, const float* __restrict__ bias2,
    float* __restrict__ outF, bf16_t* __restrict__ outB, bf16_t* __restrict__ outB2,
    int M, int N, int K, int p0, int ldo, int gm)
{
    __shared__ bf16_t sm[32768];
    gemm128_body<EPI>(sm, blockIdx.x, gridDim.x, A, Bt, bias, bias2,
                      outF, outB, outB2, M, N, K, p0, ldo, gm);
}

// Fused Q + KV projection: blocks [0,256) Q-GEMM, [256,832) KV-GEMM.
__global__ __launch_bounds__(256) void qkv_fused(
    const bf16_t* __restrict__ hbuf, const bf16_t* __restrict__ kvbuf,
    const bf16_t* __restrict__ wtq, const bf16_t* __restrict__ wtkv,
    const float* __restrict__ bq, const float* __restrict__ bk,
    const float* __restrict__ bv,
    bf16_t* __restrict__ qbuf, bf16_t* __restrict__ kbuf, bf16_t* __restrict__ vtbuf)
{
    __shared__ bf16_t sm[32768];
    if (blockIdx.x < 256) {
        gemm128_body<EPI_QKV>(sm, blockIdx.x, 256, hbuf, wtq, bq, nullptr,
                              nullptr, qbuf, nullptr, NB * NT, NC, NC, NT, 0, 8);
    } else {
        gemm128_body<EPI_KV>(sm, blockIdx.x - 256, 576, kvbuf, wtkv, bk, bv,
                             nullptr, kbuf, vtbuf, NB * NTK, 2 * NC, NC, NTK, 0, 6);
    }
}

// ---------------------------------------------------------------------------
// Legacy 128x128/BK=32 GEMM (only for tiny m2 GEMM).
// ---------------------------------------------------------------------------
template<int EPI>
__global__ __launch_bounds__(256) void gemm_bt(
    const bf16_t* __restrict__ A, const bf16_t* __restrict__ Bt,
    const float* __restrict__ bias, const float* __restrict__ bias2,
    float* __restrict__ outF, bf16_t* __restrict__ outB, bf16_t* __restrict__ outB2,
    int M, int N, int K, int p0, int ldo, int gm)
{
    __shared__ bf16_t lA[128 * 32];
    __shared__ bf16_t lB[128 * 32];
    const int tid = threadIdx.x;
    const int nwg = gridDim.x;
    const int bid = blockIdx.x;
    const int xcd = bid & 7, base = bid >> 3;
    const int qq = nwg >> 3, rr = nwg & 7;
    int wg = (xcd < rr ? xcd * (qq + 1) : rr * (qq + 1) + (xcd - rr) * qq) + base;
    const int nnt = N >> 7;
    const int gsz = gm * nnt;
    const int g = wg / gsz, r2 = wg - g * gsz;
    const int ntl = r2 / gm, mt = g * gm + (r2 - ntl * gm);
    const int bm = mt * 128, bn = ntl * 128;
    const bf16_t* Ab = A + (size_t)bm * K;
    const bf16_t* Bb = Bt + (size_t)bn * K;
    const int wave = tid >> 6, lane = tid & 63;
    const int wr = wave >> 1, wc = wave & 1;
    const int lr = lane & 15, lk = lane >> 4;
    f32x4 acc[4][4] = {};
    const int nk = K >> 5;
    const int c1 = tid, c2 = tid + 256;
    for (int kt = 0; kt < nk; ++kt) {
        __syncthreads();
        const bf16_t* Abk = Ab + kt * 32;
        const bf16_t* Bbk = Bb + kt * 32;
        GLOAD_LDS16(Abk + (size_t)(c1 >> 2) * K + (c1 & 3) * 8, (char*)lA + c1 * 16);
        GLOAD_LDS16(Abk + (size_t)(c2 >> 2) * K + (c2 & 3) * 8, (char*)lA + c2 * 16);
        GLOAD_LDS16(Bbk + (size_t)(c1 >> 2) * K + (c1 & 3) * 8, (char*)lB + c1 * 16);
        GLOAD_LDS16(Bbk + (size_t)(c2 >> 2) * K + (c2 & 3) * 8, (char*)lB + c2 * 16);
        __syncthreads();
        bf16x8 af[4], bfr[4];
        #pragma unroll
        for (int m = 0; m < 4; ++m)
            af[m] = *(const bf16x8*)&lA[(wr * 64 + m * 16 + lr) * 32 + lk * 8];
        #pragma unroll
        for (int n = 0; n < 4; ++n)
            bfr[n] = *(const bf16x8*)&lB[(wc * 64 + n * 16 + lr) * 32 + lk * 8];
        #pragma unroll
        for (int m = 0; m < 4; ++m)
            #pragma unroll
            for (int n = 0; n < 4; ++n)
                acc[m][n] = __builtin_amdgcn_mfma_f32_16x16x32_bf16(af[m], bfr[n], acc[m][n], 0, 0, 0);
    }
    #pragma unroll
    for (int m = 0; m < 4; ++m) {
        #pragma unroll
        for (int j = 0; j < 4; ++j) {
            const int row = bm + wr * 64 + m * 16 + lk * 4 + j;
            #pragma unroll
            for (int n = 0; n < 4; ++n) {
                const int col = bn + wc * 64 + n * 16 + lr;
                if constexpr (EPI == EPI_F32) {
                    float v = acc[m][n][j] + bias[col];
                    __builtin_nontemporal_store(v, &outF[(size_t)row * ldo + col]);
                }
            }
        }
    }
}

// ---------------------------------------------------------------------------
// Transpose+cast body
// ---------------------------------------------------------------------------
__device__ __forceinline__ void tc_body(
    const float* __restrict__ W, bf16_t* __restrict__ Wt,
    int K, int N, int k0, int n0, int t)
{
    __shared__ float tile[64][65];
    #pragma unroll
    for (int i = 0; i < 4; ++i) {
        const int idx = t + i * 256;
        const int r = idx >> 4, c4 = (idx & 15) << 2;
        const float4 v = *(const float4*)(W + (size_t)(k0 + r) * N + n0 + c4);
        tile[r][c4 + 0] = v.x; tile[r][c4 + 1] = v.y;
        tile[r][c4 + 2] = v.z; tile[r][c4 + 3] = v.w;
    }
    __syncthreads();
    #pragma unroll
    for (int i = 0; i < 4; ++i) {
        const int idx = t + i * 256;
        const int r = idx >> 4, c4 = (idx & 15) << 2;
        bf16x4 o = {(bf16_t)tile[c4 + 0][r], (bf16_t)tile[c4 + 1][r],
                    (bf16_t)tile[c4 + 2][r], (bf16_t)tile[c4 + 3][r]};
        *(bf16x4*)(Wt + (size_t)(n0 + r) * K + k0 + c4) = o;
    }
}

__global__ __launch_bounds__(256) void transpose_cast(
    const float* __restrict__ W, bf16_t* __restrict__ Wt, int K, int N)
{
    tc_body(W, Wt, K, N, blockIdx.x << 6, blockIdx.y << 6, threadIdx.x);
}

// ---------------------------------------------------------------------------
// LN body (ln1 + x->kv cast), used by prep_layer.
// ---------------------------------------------------------------------------
__device__ __forceinline__ void ln3_body(
    int row, const float* __restrict__ X, const float* __restrict__ sw,
    const float* __restrict__ bw, bf16_t* __restrict__ outB,
    bf16_t* __restrict__ outB2)
{
    const int t = threadIdx.x;
    const float4 v = ((const float4*)(X + (size_t)row * NC))[t];
    float s1 = v.x + v.y + v.z + v.w;
    float s2 = v.x * v.x + v.y * v.y + v.z * v.z + v.w * v.w;
    #pragma unroll
    for (int off = 32; off > 0; off >>= 1) { s1 += __shfl_xor(s1, off); s2 += __shfl_xor(s2, off); }
    __shared__ float rs1[4], rs2[4];
    if ((t & 63) == 0) { rs1[t >> 6] = s1; rs2[t >> 6] = s2; }
    __syncthreads();
    s1 = rs1[0] + rs1[1] + rs1[2] + rs1[3];
    s2 = rs2[0] + rs2[1] + rs2[2] + rs2[3];
    const float mu = s1 * (1.0f / NC);
    const float var = s2 * (1.0f / NC) - mu * mu;
    const float rstd = rsqrtf(var + 1e-6f);
    const int c = t * 4;
    const float4 sv = ((const float4*)sw)[t];
    const float4 bv = ((const float4*)bw)[t];
    float y0 = (v.x - mu) * rstd * sv.x + bv.x;
    float y1 = (v.y - mu) * rstd * sv.y + bv.y;
    float y2 = (v.z - mu) * rstd * sv.z + bv.z;
    float y3 = (v.w - mu) * rstd * sv.w + bv.w;
    bf16x4 o = {(bf16_t)y0, (bf16_t)y1, (bf16_t)y2, (bf16_t)y3};
    *(bf16x4*)(outB + (size_t)row * NC + c) = o;
    const int b_ = row >> 10, t_ = row & 1023;
    bf16x4 o2 = {(bf16_t)v.x, (bf16_t)v.y, (bf16_t)v.z, (bf16_t)v.w};
    *(bf16x4*)(outB2 + ((size_t)b_ * NTK + NO + t_) * NC + c) = o2;
}

// Fused per-layer prep: blocks [0,3072) transpose 6 weights (JIT),
// blocks [3072,7168) = ln1 + x->kv cast. Independent work, one launch.
__global__ __launch_bounds__(256) void prep_layer(
    const float* __restrict__ Wq, const float* __restrict__ Wk,
    const float* __restrict__ Wv, const float* __restrict__ Wo,
    const float* __restrict__ W1, const float* __restrict__ W2,
    bf16_t* __restrict__ wtq, bf16_t* __restrict__ wtkv,
    bf16_t* __restrict__ wto, bf16_t* __restrict__ wt1, bf16_t* __restrict__ wt2,
    const float* __restrict__ X, const float* __restrict__ ln1s,
    const float* __restrict__ ln1b, bf16_t* __restrict__ hbuf,
    bf16_t* __restrict__ kvbuf)
{
    const int bid = blockIdx.x;
    if (bid >= 3072) {
        ln3_body(bid - 3072, X, ln1s, ln1b, hbuf, kvbuf);
        return;
    }
    const float* W; bf16_t* Wt; int K, N, k0, n0;
    if (bid < 1024) {
        const int which = bid >> 8, r = bid & 255;
        K = NC; N = NC;
        k0 = (r & 15) << 6; n0 = (r >> 4) << 6;
        W  = (which == 0) ? Wq : (which == 1) ? Wk : (which == 2) ? Wv : Wo;
        Wt = (which == 0) ? wtq : (which == 1) ? wtkv
           : (which == 2) ? (wtkv + (size_t)NC * NC) : wto;
    } else if (bid < 2048) {
        const int r = bid - 1024;
        K = NC; N = 4 * NC;
        k0 = (r & 15) << 6; n0 = (r >> 4) << 6;
        W = W1; Wt = wt1;
    } else {
        const int r = bid - 2048;
        K = 4 * NC; N = NC;
        k0 = (r & 63) << 6; n0 = (r >> 6) << 6;
        W = W2; Wt = wt2;
    }
    tc_body(W, Wt, K, N, k0, n0, threadIdx.x);
}

// ---------------------------------------------------------------------------
// LayerNorm over C=1024. MODE 0: bf16 natural; 1: kv-m2 row remap.
// ---------------------------------------------------------------------------
template<int MODE>
__global__ __launch_bounds__(256) void ln_row(
    const float* __restrict__ X, const float* __restrict__ sw,
    const float* __restrict__ bw, float* __restrict__ outF,
    bf16_t* __restrict__ outB, bf16_t* __restrict__ outB2)
{
    const int row = blockIdx.x;
    const int t = threadIdx.x;
    const float4 v = ((const float4*)(X + (size_t)row * NC))[t];
    float s1 = v.x + v.y + v.z + v.w;
    float s2 = v.x * v.x + v.y * v.y + v.z * v.z + v.w * v.w;
    #pragma unroll
    for (int off = 32; off > 0; off >>= 1) { s1 += __shfl_xor(s1, off); s2 += __shfl_xor(s2, off); }
    __shared__ float rs1[4], rs2[4];
    if ((t & 63) == 0) { rs1[t >> 6] = s1; rs2[t >> 6] = s2; }
    __syncthreads();
    s1 = rs1[0] + rs1[1] + rs1[2] + rs1[3];
    s2 = rs2[0] + rs2[1] + rs2[2] + rs2[3];
    const float mu = s1 * (1.0f / NC);
    const float var = s2 * (1.0f / NC) - mu * mu;
    const float rstd = rsqrtf(var + 1e-6f);
    const int c = t * 4;
    const float4 sv = ((const float4*)sw)[t];
    const float4 bv = ((const float4*)bw)[t];
    float y0 = (v.x - mu) * rstd * sv.x + bv.x;
    float y1 = (v.y - mu) * rstd * sv.y + bv.y;
    float y2 = (v.z - mu) * rstd * sv.z + bv.z;
    float y3 = (v.w - mu) * rstd * sv.w + bv.w;
    size_t dst;
    if constexpr (MODE == 1) dst = ((size_t)(row / NO) * NTK + (row % NO)) * NC + c;
    else dst = (size_t)row * NC + c;
    bf16x4 o = {(bf16_t)y0, (bf16_t)y1, (bf16_t)y2, (bf16_t)y3};
    *(bf16x4*)(outB + dst) = o;
}

// ---------------------------------------------------------------------------
// Final LN fused with mask-cast + new_mem extraction.
// ---------------------------------------------------------------------------
__global__ __launch_bounds__(256) void ln_final(
    const float* __restrict__ X, const float* __restrict__ sw,
    const float* __restrict__ bw, const int* __restrict__ tokens,
    bf16_t* __restrict__ xm, float* __restrict__ outMem)
{
    const int row = blockIdx.x;
    const int t = threadIdx.x;
    const float4 v = ((const float4*)(X + (size_t)row * NC))[t];
    float s1 = v.x + v.y + v.z + v.w;
    float s2 = v.x * v.x + v.y * v.y + v.z * v.z + v.w * v.w;
    #pragma unroll
    for (int off = 32; off > 0; off >>= 1) { s1 += __shfl_xor(s1, off); s2 += __shfl_xor(s2, off); }
    __shared__ float rs1[4], rs2[4];
    if ((t & 63) == 0) { rs1[t >> 6] = s1; rs2[t >> 6] = s2; }
    __syncthreads();
    s1 = rs1[0] + rs1[1] + rs1[2] + rs1[3];
    s2 = rs2[0] + rs2[1] + rs2[2] + rs2[3];
    const float mu = s1 * (1.0f / NC);
    const float var = s2 * (1.0f / NC) - mu * mu;
    const float rstd = rsqrtf(var + 1e-6f);
    const int c = t * 4;
    const float4 sv = ((const float4*)sw)[t];
    const float4 bv = ((const float4*)bw)[t];
    float y0 = (v.x - mu) * rstd * sv.x + bv.x;
    float y1 = (v.y - mu) * rstd * sv.y + bv.y;
    float y2 = (v.z - mu) * rstd * sv.z + bv.z;
    float y3 = (v.w - mu) * rstd * sv.w + bv.w;
    const bool ok = tokens[row] != 0;
    bf16x4 o;
    if (ok) { o = (bf16x4){(bf16_t)y0, (bf16_t)y1, (bf16_t)y2, (bf16_t)y3}; }
    else    { o = (bf16x4){(bf16_t)0.f, (bf16_t)0.f, (bf16_t)0.f, (bf16_t)0.f}; }
    *(bf16x4*)(xm + (size_t)row * NC + c) = o;
    const int b_ = row >> 10, t_ = row & 1023;
    if (t_ >= NT - NO) {
        float4 f; f.x = y0; f.y = y1; f.z = y2; f.w = y3;
        *(float4*)(outMem + ((size_t)b_ * NO + (t_ - (NT - NO))) * NC + c) = f;
    }
}

// ---------------------------------------------------------------------------
// Flash attention: 32 q-rows per wave, 4 waves/block, no barriers, 64-key
// tiles, LPT y-order. Softmax in exp2 domain.
// ---------------------------------------------------------------------------
#define QKSCALE 0.1803368801111204f   // 0.125 * log2(e)

__global__ __launch_bounds__(256) void attn_kernel(
    const bf16_t* __restrict__ Q, const bf16_t* __restrict__ Kb,
    const bf16_t* __restrict__ Vt, const int* __restrict__ tokens,
    bf16_t* __restrict__ Ob)
{
    const int bh = blockIdx.x;
    const int b = bh >> 4, h = bh & 15;
    const int w = threadIdx.x >> 6;
    const int lane = threadIdx.x & 63;
    const int yt = gridDim.y - 1 - blockIdx.y;   // LPT: long tiles first
    const int q0 = (yt << 7) + (w << 5);
    const int lr = lane & 15, lk = lane >> 4;
    const bf16_t* Qp = Q + ((size_t)bh * NT + q0) * ND;
    bf16x8 qf[2][2];
    #pragma unroll
    for (int qs = 0; qs < 2; ++qs) {
        qf[qs][0] = *(const bf16x8*)(Qp + (qs * 16 + lr) * ND + lk * 8);
        qf[qs][1] = *(const bf16x8*)(Qp + (qs * 16 + lr) * ND + 32 + lk * 8);
    }
    const bf16_t* Kbase = Kb + (size_t)bh * NTK * ND;
    const bf16_t* Vbase = Vt + (size_t)bh * ND * NTK;
    const int* tokb = tokens + b * NT;
    float mrow[2][4] = {{-1e30f, -1e30f, -1e30f, -1e30f}, {-1e30f, -1e30f, -1e30f, -1e30f}};
    float lsum[2][4] = {};
    f32x4 acc[2][4] = {};
    __shared__ bf16_t pb[4][2][16 * 64];
    const int kmax = NO + q0 + 32;
    for (int k0 = 0; k0 < kmax; k0 += 64) {
        f32x4 st[2][4] = {};
        __builtin_amdgcn_s_setprio(1);
        #pragma unroll
        for (int nt = 0; nt < 4; ++nt) {
            const bf16_t* Kp = Kbase + (size_t)(k0 + nt * 16 + lr) * ND + lk * 8;
            bf16x8 kf0 = *(const bf16x8*)(Kp);
            bf16x8 kf1 = *(const bf16x8*)(Kp + 32);
            #pragma unroll
            for (int qs = 0; qs < 2; ++qs) {
                st[qs][nt] = __builtin_amdgcn_mfma_f32_16x16x32_bf16(qf[qs][0], kf0, st[qs][nt], 0, 0, 0);
                st[qs][nt] = __builtin_amdgcn_mfma_f32_16x16x32_bf16(qf[qs][1], kf1, st[qs][nt], 0, 0, 0);
            }
        }
        __builtin_amdgcn_s_setprio(0);
        #pragma unroll
        for (int qs = 0; qs < 2; ++qs) {
            char* pbq = (char*)pb[w][qs];
            float sc[4][4];
            float tmax[4] = {-1e30f, -1e30f, -1e30f, -1e30f};
            #pragma unroll
            for (int nt = 0; nt < 4; ++nt) {
                const int key = k0 + nt * 16 + lr;
                const int kt = key - NO;
                const int kts = kt < 0 ? 0 : kt;
                const bool keyok = (kt < 0) | (tokb[kts] != 0);
                #pragma unroll
                for (int j = 0; j < 4; ++j) {
                    const int qrow = q0 + qs * 16 + lk * 4 + j;
                    const bool ok = keyok && (kt <= qrow);
                    const float s = ok ? st[qs][nt][j] * QKSCALE : -1e9f;
                    sc[nt][j] = s;
                    tmax[j] = fmaxf(tmax[j], s);
                }
            }
            #pragma unroll
            for (int off = 1; off < 16; off <<= 1)
                #pragma unroll
                for (int j = 0; j < 4; ++j) tmax[j] = fmaxf(tmax[j], __shfl_xor(tmax[j], off));
            float resc[4], p[4][4], psum[4] = {0.f, 0.f, 0.f, 0.f};
            #pragma unroll
            for (int j = 0; j < 4; ++j) {
                const float mnew = fmaxf(mrow[qs][j], tmax[j]);
                resc[j] = EXP2F(mrow[qs][j] - mnew);
                mrow[qs][j] = mnew;
            }
            #pragma unroll
            for (int nt = 0; nt < 4; ++nt)
                #pragma unroll
                for (int j = 0; j < 4; ++j) { p[nt][j] = EXP2F(sc[nt][j] - mrow[qs][j]); psum[j] += p[nt][j]; }
            #pragma unroll
            for (int off = 1; off < 16; off <<= 1)
                #pragma unroll
                for (int j = 0; j < 4; ++j) psum[j] += __shfl_xor(psum[j], off);
            #pragma unroll
            for (int j = 0; j < 4; ++j) lsum[qs][j] = lsum[qs][j] * resc[j] + psum[j];
            #pragma unroll
            for (int dt = 0; dt < 4; ++dt)
                #pragma unroll
                for (int j = 0; j < 4; ++j) acc[qs][dt][j] *= resc[j];
            #pragma unroll
            for (int nt = 0; nt < 4; ++nt)
                #pragma unroll
                for (int j = 0; j < 4; ++j) {
                    const int row = lk * 4 + j;
                    const int byt = (row << 7) + ((((nt << 4) + lr) << 1) ^ ((row & 7) << 4));
                    *(bf16_t*)(pbq + byt) = (bf16_t)p[nt][j];
                }
        }
        const int swz = (lr & 7) << 4;
        bf16x8 pa[2][2];
        #pragma unroll
        for (int qs = 0; qs < 2; ++qs) {
            const char* pbq = (const char*)pb[w][qs];
            pa[qs][0] = *(const bf16x8*)(pbq + ((lr << 7) + (((lk << 4)) ^ swz)));
            pa[qs][1] = *(const bf16x8*)(pbq + ((lr << 7) + ((64 + (lk << 4)) ^ swz)));
        }
        __builtin_amdgcn_s_setprio(1);
        #pragma unroll
        for (int dt = 0; dt < 4; ++dt) {
            const bf16_t* Vp = Vbase + (size_t)(dt * 16 + lr) * NTK + k0 + lk * 8;
            bf16x8 vf0 = *(const bf16x8*)(Vp);
            bf16x8 vf1 = *(const bf16x8*)(Vp + 32);
            #pragma unroll
            for (int qs = 0; qs < 2; ++qs) {
                acc[qs][dt] = __builtin_amdgcn_mfma_f32_16x16x32_bf16(pa[qs][0], vf0, acc[qs][dt], 0, 0, 0);
                acc[qs][dt] = __builtin_amdgcn_mfma_f32_16x16x32_bf16(pa[qs][1], vf1, acc[qs][dt], 0, 0, 0);
            }
        }
        __builtin_amdgcn_s_setprio(0);
    }
    #pragma unroll
    for (int qs = 0; qs < 2; ++qs)
        #pragma unroll
        for (int dt = 0; dt < 4; ++dt)
            #pragma unroll
            for (int j = 0; j < 4; ++j)
                Ob[((size_t)b * NT + q0 + qs * 16 + lk * 4 + j) * NC + h * ND + dt * 16 + lr] =
                    (bf16_t)(acc[qs][dt][j] / lsum[qs][j]);
}

// ---------------------------------------------------------------------------
// Small kernels
// ---------------------------------------------------------------------------
__global__ __launch_bounds__(256) void sum_proj_kernel(
    const float* __restrict__ ssum, const float* __restrict__ sumw,
    const float* __restrict__ alpha, float* __restrict__ add)
{
    const int b = blockIdx.y;
    const int c = blockIdx.x * 256 + threadIdx.x;
    float a = 0.f;
    for (int k = 0; k < NC; ++k) a += ssum[b * NC + k] * sumw[(size_t)k * NC + c];
    add[b * NC + c] = a * sigmoidf_(alpha[c]);
}

__global__ __launch_bounds__(256) void embed_kernel(
    const int* __restrict__ tokens, const int* __restrict__ posoff,
    const float* __restrict__ tokw, const float* __restrict__ posw,
    const float* __restrict__ add, float* __restrict__ X)
{
    const int bt = blockIdx.x;
    const int b = bt >> 10, t = bt & 1023;
    const int c = threadIdx.x * 4;
    const int tok = tokens[bt];
    int p = t + posoff[0];
    p = p < 0 ? 0 : (p > NS - 1 ? NS - 1 : p);
    const float4 tv = *(const float4*)(tokw + (size_t)tok * NC + c);
    const float4 pv = *(const float4*)(posw + (size_t)p * NC + c);
    const float4 av = *(const float4*)(add + b * NC + c);
    float4 o;
    o.x = tv.x + pv.x + av.x; o.y = tv.y + pv.y + av.y;
    o.z = tv.z + pv.z + av.z; o.w = tv.w + pv.w + av.w;
    *(float4*)(X + (size_t)bt * NC + c) = o;
}

__global__ __launch_bounds__(256) void cast_f32_bf16_kernel(
    const float* __restrict__ in, bf16_t* __restrict__ out)
{
    const size_t i = ((size_t)blockIdx.x * 256 + threadIdx.x) * 4;
    const float4 v = *(const float4*)(in + i);
    bf16x4 o = {(bf16_t)v.x, (bf16_t)v.y, (bf16_t)v.z, (bf16_t)v.w};
    *(bf16x4*)(out + i) = o;
}

__global__ __launch_bounds__(256) void sumpart_kernel(
    const bf16_t* __restrict__ XM, float* __restrict__ sbuf)
{
    const int b = blockIdx.z;
    const int c = blockIdx.x * 256 + threadIdx.x;
    const int t0 = blockIdx.y * 64;
    float a = 0.f;
    for (int t = t0; t < t0 + 64; ++t)
        a += (float)XM[((size_t)b * NT + t) * NC + c];
    atomicAdd(&sbuf[b * NC + c], a);
}

__global__ __launch_bounds__(256) void ssum_out_kernel(
    const float* __restrict__ sbuf, const int* __restrict__ tokens,
    const float* __restrict__ ssum, const float* __restrict__ lamp, float* __restrict__ out)
{
    const int b = blockIdx.y;
    const int c = blockIdx.x * 256 + threadIdx.x;
    int cnt = 0;
    for (int t = 0; t < NT; ++t) cnt += (tokens[b * NT + t] != 0);
    const float summary = sbuf[b * NC + c] / ((float)cnt + 1e-6f);
    const float lam = sigmoidf_(lamp[c]);
    out[b * NC + c] = ssum[b * NC + c] * lam + summary * (1.0f - lam);
}

// ---------------------------------------------------------------------------
extern "C" void kernel_launch(void* const* d_in, const int* in_sizes, int n_in,
                              void* d_out, int out_size, void* d_ws, size_t ws_size,
                              hipStream_t stream)
{
    (void)in_sizes; (void)n_in; (void)out_size; (void)ws_size;
    const int*   tokens   = (const int*)d_in[0];
    const int*   posoff   = (const int*)d_in[1];
    const float* mem      = (const float*)d_in[2];
    const float* ssum     = (const float*)d_in[3];
    const float* tok_emb  = (const float*)d_in[4];
    const float* pos_emb  = (const float*)d_in[5];
    const float* mem_w    = (const float*)d_in[6];
    const float* mem_b    = (const float*)d_in[7];
    const float* memln_s  = (const float*)d_in[8];
    const float* memln_b  = (const float*)d_in[9];
    const float* alpha_p  = (const float*)d_in[10];
    const float* sum_w    = (const float*)d_in[11];
    const float* ln1_s    = (const float*)d_in[12];
    const float* ln1_b    = (const float*)d_in[13];
    const float* Wq       = (const float*)d_in[14];
    const float* bq       = (const float*)d_in[15];
    const float* Wk       = (const float*)d_in[16];
    const float* bk       = (const float*)d_in[17];
    const float* Wv       = (const float*)d_in[18];
    const float* bv       = (const float*)d_in[19];
    const float* Wo       = (const float*)d_in[20];
    const float* bo       = (const float*)d_in[21];
    const float* ln2_s    = (const float*)d_in[22];
    const float* ln2_b    = (const float*)d_in[23];
    const float* W1       = (const float*)d_in[24];
    const float* b1       = (const float*)d_in[25];
    const float* W2       = (const float*)d_in[26];
    const float* b2       = (const float*)d_in[27];
    const float* fln_s    = (const float*)d_in[28];
    const float* fln_b    = (const float*)d_in[29];
    const float* head_w   = (const float*)d_in[30];
    const float* head_b   = (const float*)d_in[31];
    const float* lam_p    = (const float*)d_in[32];

    float* out_mem    = (float*)d_out;                          // B*O*C
    float* out_ssum   = out_mem + (size_t)NB * NO * NC;         // B*C
    float* out_logits = out_ssum + (size_t)NB * NC;             // B*T*V

    char* wp = (char*)d_ws;
    auto alloc = [&](size_t bytes) { char* p = wp; wp += (bytes + 255) & ~(size_t)255; return p; };
    bf16_t* wt_head = (bf16_t*)alloc((size_t)NV * NC * 2);
    bf16_t* wt_mem  = (bf16_t*)alloc((size_t)NC * NC * 2);
    bf16_t* wt_q    = (bf16_t*)alloc((size_t)NC * NC * 2);
    bf16_t* wt_kv   = (bf16_t*)alloc((size_t)2 * NC * NC * 2);
    bf16_t* wt_o    = (bf16_t*)alloc((size_t)NC * NC * 2);
    bf16_t* wt_1    = (bf16_t*)alloc((size_t)NC * 4 * NC * 2);
    bf16_t* wt_2    = (bf16_t*)alloc((size_t)NC * 4 * NC * 2);
    float*  xbuf    = (float*)alloc((size_t)NB * NT * NC * 4);
    bf16_t* hbuf    = (bf16_t*)alloc((size_t)NB * NT * NC * 2);
    bf16_t* kvbuf   = (bf16_t*)alloc((size_t)NB * NTK * NC * 2);
    bf16_t* qbuf    = (bf16_t*)alloc((size_t)NB * NT * NC * 2);
    bf16_t* kbuf    = (bf16_t*)alloc((size_t)NB * NTK * NC * 2);
    bf16_t* vtbuf   = (bf16_t*)alloc((size_t)NB * NTK * NC * 2);
    bf16_t* obuf    = (bf16_t*)alloc((size_t)NB * NT * NC * 2);
    bf16_t* midbuf  = (bf16_t*)alloc((size_t)NB * NT * 4 * NC * 2);
    bf16_t* xmbuf   = (bf16_t*)alloc((size_t)NB * NT * NC * 2);
    bf16_t* membf   = (bf16_t*)alloc((size_t)NB * NO * NC * 2);
    float*  m2f     = (float*)alloc((size_t)NB * NO * NC * 4);
    float*  addb    = (float*)alloc((size_t)NB * NC * 4);
    float*  sbuf    = (float*)alloc((size_t)NB * NC * 4);

    (void)hipMemsetAsync(sbuf, 0, (size_t)NB * NC * 4, stream);

    // mem weight transpose (consumed immediately below)
    transpose_cast<<<dim3(NC / 64, NC / 64), 256, 0, stream>>>(mem_w, wt_mem, NC, NC);

    // m2 = LN(mem @ mem_w + mem_b) -> kv rows [0,O)
    cast_f32_bf16_kernel<<<(NB * NO * NC) / 1024, 256, 0, stream>>>(mem, membf);
    gemm_bt<EPI_F32><<<32, 256, 0, stream>>>(
        membf, wt_mem, mem_b, nullptr, m2f, nullptr, nullptr, NB * NO, NC, NC, 0, NC, 4);
    ln_row<1><<<NB * NO, 256, 0, stream>>>(m2f, memln_s, memln_b, nullptr, kvbuf, nullptr);

    // x = tok_emb[tokens] + pos_emb + (ssum @ sum_w)*sigmoid(alpha)
    sum_proj_kernel<<<dim3(NC / 256, NB), 256, 0, stream>>>(ssum, sum_w, alpha_p, addb);
    embed_kernel<<<NB * NT, 256, 0, stream>>>(tokens, posoff, tok_emb, pos_emb, addb, xbuf);

    for (int i = 0; i < NL; ++i) {
        // fused: JIT weight transposes + (ln1 + x->kv cast), one launch
        prep_layer<<<7168, 256, 0, stream>>>(
            Wq + (size_t)i * NC * NC, Wk + (size_t)i * NC * NC,
            Wv + (size_t)i * NC * NC, Wo + (size_t)i * NC * NC,
            W1 + (size_t)i * NC * 4 * NC, W2 + (size_t)i * 4 * NC * NC,
            wt_q, wt_kv, wt_o, wt_1, wt_2,
            xbuf, ln1_s + i * NC, ln1_b + i * NC, hbuf, kvbuf);

        // Q + KV projections fused into ONE launch (832 blocks)
        qkv_fused<<<832, 256, 0, stream>>>(
            hbuf, kvbuf, wt_q, wt_kv, bq + i * NC, bk + i * NC, bv + i * NC,
            qbuf, kbuf, vtbuf);

        attn_kernel<<<dim3(NB * NH, NT / 128), 256, 0, stream>>>(qbuf, kbuf, vtbuf, tokens, obuf);

        gemm128<EPI_ADD><<<256, 256, 0, stream>>>(
            obuf, wt_o, bo + i * NC, nullptr, xbuf, nullptr, nullptr, NB * NT, NC, NC, 0, NC, 8);

        ln_row<0><<<NB * NT, 256, 0, stream>>>(xbuf, ln2_s + i * NC, ln2_b + i * NC, nullptr, hbuf, nullptr);
        // FFN1: 256^2 engine (GELU epilogue)
        gemm8p<1><<<256, 512, 0, stream>>>(
            hbuf, wt_1, b1 + (size_t)i * 4 * NC, nullptr, midbuf, NB * NT, 4 * NC, NC, 4 * NC, 4);
        // FFN2
        gemm128<EPI_ADD><<<256, 256, 0, stream>>>(
            midbuf, wt_2, b2 + i * NC, nullptr, xbuf, nullptr, nullptr, NB * NT, NC, 4 * NC, 0, NC, 8);
    }

    // final LN fused with mask-cast + new_mem extraction
    ln_final<<<NB * NT, 256, 0, stream>>>(xbuf, fln_s, fln_b, tokens, xmbuf, out_mem);
    sumpart_kernel<<<dim3(NC / 256, NT / 64, NB), 256, 0, stream>>>(xmbuf, sbuf);
    ssum_out_kernel<<<dim3(NC / 256, NB), 256, 0, stream>>>(sbuf, tokens, ssum, lam_p, out_ssum);
    // head weight transpose JIT (L3-warm for the head GEMM right below;
    // round-13 lesson: distance-to-use determines L3 warmth)
    transpose_cast<<<dim3(NC / 64, NV / 64), 256, 0, stream>>>(head_w, wt_head, NC, NV);
    // head: 256^2 engine
    gemm8p<0><<<2000, 512, 0, stream>>>(
        xmbuf, wt_head, head_b, out_logits, nullptr, NB * NT, NV, NC, NV, 4);
}